// Round 2
// baseline (1387.483 us; speedup 1.0000x reference)
//
#include <hip/hip_runtime.h>
#include <hip/hip_bf16.h>
#include <math.h>

// Problem constants
static constexpr int  Bn = 8, Dn = 1024, Ln = 2048;
static constexpr long DL  = (long)Dn * Ln;
static constexpr long DDm = (long)Dn * Dn;
static constexpr long LLm = (long)Ln * Ln;
static constexpr float P_EXP = 1.01005016708416805754f; // exp(0.01)
static constexpr float PI_F  = 3.14159265358979323846f;

using bf = __hip_bfloat16;
typedef short s16x8 __attribute__((ext_vector_type(8)));   // 8 bf16 = 4 VGPRs (MFMA A/B frag)
typedef float f32x4 __attribute__((ext_vector_type(4)));   // MFMA C/D frag

#define GPTR(x) ((const __attribute__((address_space(1))) void*)(x))
#define LPTR(x) ((__attribute__((address_space(3))) void*)(x))

enum { EPI_BIAS = 0, EPI_PLAIN = 1, EPI_CAUCHY = 2, EPI_RESID = 3, EPI_BIASM = 4, EPI_CAUCHYB = 5 };

// bf16 RNE pack (finite values only)
static __device__ inline unsigned short f2bf_rne(float f)
{
    union { float f; unsigned u; } uf; uf.f = f;
    unsigned r = uf.u + 0x7fff + ((uf.u >> 16) & 1);
    return (unsigned short)(r >> 16);
}
static __device__ inline float bf2f(unsigned short s)
{
    union { unsigned u; float f; } uf; uf.u = ((unsigned)s) << 16;
    return uf.f;
}

struct P4 { const float* p[4]; };

// ---------------------------------------------------------------------------
// NT bf16 MFMA GEMM: C[b,m,n] = sum_k A[b,m,k] * Bt[b,n,k]   (both k-contig)
// 128x128 tile, BK=32, 256 threads (4 waves, 2x2 of 64x64 wave tiles).
// 4 blocks/CU resident -> epilogue (incl. transcendental CAUCHY) overlaps
// other blocks' K-loops. Keep ALL heavy-epilogue GEMMs here.
// ---------------------------------------------------------------------------
template<int EPI>
__global__ __launch_bounds__(256, 4)
void gemm_nt(const short* __restrict__ A, long sAb, int ldA,
             const short* __restrict__ Bt, long sBb, int ldB,
             void* __restrict__ Cv, long sCb, int ldC,
             const float* __restrict__ bias,
             const float* __restrict__ rowN, const float* __restrict__ colN,
             const float* __restrict__ resid, long sRb,
             int M, int N, int K)
{
    __shared__ short As[128 * 32];   // row-major, 32 bf16 per row, k-chunk swizzled
    __shared__ short Bs[128 * 32];

    const int tid  = threadIdx.x;
    const int lane = tid & 63;
    const int w    = tid >> 6;           // wave 0..3
    const int wm   = w >> 1, wn = w & 1; // 2x2 wave grid
    const int m0   = blockIdx.y * 128;
    const int n0   = blockIdx.x * 128;
    const int bz   = blockIdx.z;

    const short* Ab = A  + (long)bz * sAb;
    const short* Bb = Bt + (long)bz * sBb;

    const int srow = lane >> 2;                                  // 0..15 row within 16-row chunk
    const int kc   = ((lane & 3) + 4 - ((lane >> 3) & 3)) & 3;   // swizzled global k-chunk
    const int quad = lane >> 4;
    const int l15  = lane & 15;

    // LDS read offsets (shorts) for the 4 A / 4 B fragments
    int aoff[4], boff[4];
    #pragma unroll
    for (int i = 0; i < 4; ++i) {
        int rA = wm * 64 + i * 16 + l15;
        aoff[i] = rA * 32 + (((quad + (rA >> 1)) & 3) << 3);
        int rB = wn * 64 + i * 16 + l15;
        boff[i] = rB * 32 + (((quad + (rB >> 1)) & 3) << 3);
    }

    // staging: wave w owns 1KB chunks {2w, 2w+1} of both A and B tiles
    const int  ca0 = 2 * w;
    const long gA0 = (long)(m0 + ca0 * 16 + srow)       * ldA + kc * 8;
    const long gA1 = (long)(m0 + (ca0 + 1) * 16 + srow) * ldA + kc * 8;
    const long gB0 = (long)(n0 + ca0 * 16 + srow)       * ldB + kc * 8;
    const long gB1 = (long)(n0 + (ca0 + 1) * 16 + srow) * ldB + kc * 8;
    short* lA0 = As + ca0 * 512;
    short* lA1 = As + ca0 * 512 + 512;
    short* lB0 = Bs + ca0 * 512;
    short* lB1 = Bs + ca0 * 512 + 512;

    f32x4 acc[4][4] = {};

    for (int k0 = 0; k0 < K; k0 += 32) {
        __builtin_amdgcn_global_load_lds(GPTR(Ab + gA0 + k0), LPTR(lA0), 16, 0, 0);
        __builtin_amdgcn_global_load_lds(GPTR(Ab + gA1 + k0), LPTR(lA1), 16, 0, 0);
        __builtin_amdgcn_global_load_lds(GPTR(Bb + gB0 + k0), LPTR(lB0), 16, 0, 0);
        __builtin_amdgcn_global_load_lds(GPTR(Bb + gB1 + k0), LPTR(lB1), 16, 0, 0);
        __syncthreads();

        s16x8 af[4], bfr[4];
        #pragma unroll
        for (int i = 0; i < 4; ++i) af[i]  = *(const s16x8*)(As + aoff[i]);
        #pragma unroll
        for (int j = 0; j < 4; ++j) bfr[j] = *(const s16x8*)(Bs + boff[j]);
        #pragma unroll
        for (int i = 0; i < 4; ++i)
            #pragma unroll
            for (int j = 0; j < 4; ++j)
                acc[i][j] = __builtin_amdgcn_mfma_f32_16x16x32_bf16(af[i], bfr[j], acc[i][j], 0, 0, 0);
        __syncthreads();
    }

    // Epilogue. C/D layout: col = lane&15, row = quad*4 + r within each 16x16.
    if constexpr (EPI == EPI_BIAS || EPI == EPI_PLAIN || EPI == EPI_BIASM) {
        bf* C = (bf*)Cv + (long)bz * sCb;
        #pragma unroll
        for (int j = 0; j < 4; ++j) {
            int n = n0 + wn * 64 + j * 16 + l15;
            float bv = (EPI == EPI_BIAS) ? bias[n] : 0.f;
            #pragma unroll
            for (int i = 0; i < 4; ++i) {
                int mb = m0 + wm * 64 + i * 16 + quad * 4;
                #pragma unroll
                for (int r = 0; r < 4; ++r) {
                    float bm = (EPI == EPI_BIASM) ? bias[mb + r] : bv;
                    C[(long)(mb + r) * ldC + n] = __float2bfloat16(acc[i][j][r] + bm);
                }
            }
        }
    } else if constexpr (EPI == EPI_CAUCHY || EPI == EPI_CAUCHYB) {
        const float* rN = rowN + (long)bz * M;
        const float* cN = colN + (long)bz * N;
        #pragma unroll
        for (int j = 0; j < 4; ++j) {
            int n = n0 + wn * 64 + j * 16 + l15;
            float cn = cN[n];
            #pragma unroll
            for (int i = 0; i < 4; ++i) {
                int mb = m0 + wm * 64 + i * 16 + quad * 4;
                #pragma unroll
                for (int r = 0; r < 4; ++r) {
                    int m = mb + r;
                    float g = acc[i][j][r];
                    float ratio = (g * g) / (rN[m] * cn);
                    float o = __powf(ratio, P_EXP) - ((m == n) ? 1.f : 0.f);
                    float v = fmaxf(0.5f - 0.5f * __cosf(PI_F * o), 0.f);
                    if constexpr (EPI == EPI_CAUCHY)
                        ((float*)Cv + (long)bz * sCb)[(long)m * ldC + n] = v;
                    else
                        ((unsigned short*)Cv + (long)bz * sCb)[(long)m * ldC + n] = f2bf_rne(v);
                }
            }
        }
    } else { // EPI_RESID
        float* C = (float*)Cv + (long)bz * sCb;
        const float* Rs = resid + (long)bz * sRb;
        #pragma unroll
        for (int j = 0; j < 4; ++j) {
            int n = n0 + wn * 64 + j * 16 + l15;
            #pragma unroll
            for (int i = 0; i < 4; ++i) {
                int mb = m0 + wm * 64 + i * 16 + quad * 4;
                #pragma unroll
                for (int r = 0; r < 4; ++r) {
                    int m = mb + r;
                    C[(long)m * ldC + n] = (acc[i][j][r] + Rs[(long)m * ldC + n]) * 0.5f;
                }
            }
        }
    }
}

// ---------------------------------------------------------------------------
// 256x256 8-phase double-buffered NT GEMM (HK-schedule port). Cheap epilogues
// ONLY (BIAS/BIASM/PLAIN): 1 block/CU (128 KiB LDS) means a heavy epilogue
// has nothing to hide under, and epilogue register pressure would spill the
// 128-reg accumulator (256-reg/wave hard cap at 8 waves/block).
// ---------------------------------------------------------------------------
#define VMCNT4 asm volatile("s_waitcnt vmcnt(4)" ::: "memory")
#define VMCNT0 asm volatile("s_waitcnt vmcnt(0)" ::: "memory")
#define LGKM0  do { asm volatile("s_waitcnt lgkmcnt(0)" ::: "memory"); \
                    __builtin_amdgcn_sched_barrier(0); } while (0)

// stage one 128x64 half-tile (2 planes) : 2 x global_load_lds per thread
#define STAGE_HT(matlds, gsrc, buf, h) do {                                        \
    const short* s_ = (gsrc);                                                      \
    short* d_ = (matlds) + ((buf) * 4 + (h) * 2) * 4096 + wst;                     \
    __builtin_amdgcn_global_load_lds(GPTR(s_),      LPTR(d_),        16, 0, 0);    \
    __builtin_amdgcn_global_load_lds(GPTR(s_ + 32), LPTR(d_ + 4096), 16, 0, 0);    \
} while (0)

template<int MH>
static __device__ inline void load_a8(const short* Ad, const int (&a0)[4], s16x8 (&a)[4][2])
{
    #pragma unroll
    for (int i = 0; i < 4; ++i)
        #pragma unroll
        for (int kc = 0; kc < 2; ++kc)
            a[i][kc] = *(const s16x8*)(Ad + a0[i] + MH * 2048 + kc * 4096);
}

template<int NH>
static __device__ inline void load_b8(const short* Bd, const int (&b0)[2], s16x8 (&b)[4][2])
{
    #pragma unroll
    for (int j = 0; j < 2; ++j)
        #pragma unroll
        for (int kc = 0; kc < 2; ++kc)
            b[NH * 2 + j][kc] = *(const s16x8*)(Bd + b0[j] + NH * 1024 + kc * 4096);
}

template<int MH, int NH>
static __device__ inline void mma_q(const s16x8 (&a)[4][2], const s16x8 (&b)[4][2], f32x4 (&acc)[8][4])
{
    #pragma unroll
    for (int i = 0; i < 4; ++i)
        #pragma unroll
        for (int j = 0; j < 2; ++j)
            #pragma unroll
            for (int kc = 0; kc < 2; ++kc)
                acc[MH * 4 + i][NH * 2 + j] = __builtin_amdgcn_mfma_f32_16x16x32_bf16(
                    a[i][kc], b[NH * 2 + j][kc], acc[MH * 4 + i][NH * 2 + j], 0, 0, 0);
}

template<int EPI>
__global__ __launch_bounds__(512, 2)
void gemm_nt8(const short* __restrict__ A, long sAb, int ldA,
              const short* __restrict__ Bt, long sBb, int ldB,
              void* __restrict__ Cv, long sCb, int ldC,
              const float* __restrict__ bias,
              int M, int N, int K)
{
    __shared__ short As[32768];   // 64 KB: ((buf*2+half)*2+kc) planes of 4096 shorts
    __shared__ short Bs[32768];   // 64 KB

    const int tid  = threadIdx.x;
    const int lane = tid & 63;
    const int w    = tid >> 6;            // 0..7
    const int wm   = w >> 2, wn = w & 3;  // 2x4 wave grid; per-wave C = 128x64
    const int m0   = blockIdx.y * 256;
    const int n0   = blockIdx.x * 256;
    const int bz   = blockIdx.z;

    const short* Ab = A  + (long)bz * sAb;
    const short* Bb = Bt + (long)bz * sBb;

    const int quad = lane >> 4;
    const int l15  = lane & 15;
    const int rot  = (quad + (l15 >> 1)) & 3;   // k-chunk rotation (0-conflict, as gemm_nt)

    // LDS read offsets (shorts) within buf0; +16384 for buf1, +2048 mh1, +1024 nh1, +4096 kc1
    int a0v[4], b0v[2];
    #pragma unroll
    for (int i = 0; i < 4; ++i)
        a0v[i] = wm * 8192 + (i * 16 + l15) * 32 + rot * 8;
    #pragma unroll
    for (int j = 0; j < 2; ++j)
        b0v[j] = (wn >> 1) * 8192 + ((wn & 1) * 64 + j * 16 + l15) * 32 + rot * 8;

    // staging: wave w stages rows 16w..16w+15 of each plane; source pre-swizzled
    const int  srow = lane >> 2;
    const int  rq   = ((lane & 3) + 4 - ((lane >> 3) & 3)) & 3;
    const long gA0  = (long)(m0 + w * 16 + srow) * ldA + rq * 8;
    const long gA1  = gA0 + 128L * ldA;
    const long gB0  = (long)(n0 + w * 16 + srow) * ldB + rq * 8;
    const long gB1  = gB0 + 128L * ldB;
    const int  wst  = w * 512;            // shorts: w * 1KB

    f32x4 acc[8][4] = {};
    s16x8 a[4][2], b[4][2];

    const int NT2 = K >> 7;               // iterations of 2 K-tiles (K % 128 == 0)

    // ---- prologue: stage T0 (B then A) + B(T1); wait T0, keep B(T1) in flight
    STAGE_HT(Bs, Bb + gB0, 0, 0);
    STAGE_HT(Bs, Bb + gB1, 0, 1);
    STAGE_HT(As, Ab + gA0, 0, 0);
    STAGE_HT(As, Ab + gA1, 0, 1);
    STAGE_HT(Bs, Bb + gB0 + 64, 1, 0);
    STAGE_HT(Bs, Bb + gB1 + 64, 1, 1);
    VMCNT4;
    __builtin_amdgcn_s_barrier();

    for (int t = 0; t < NT2; ++t) {
        const long ks   = (long)t * 128;        // k offset (shorts) of T0
        const bool full = (t + 1 < NT2);
        const short* A0 = As;          const short* B0 = Bs;
        const short* A1 = As + 16384;  const short* B1 = Bs + 16384;

        // ---- ph1: q(mh0,nh0) on buf0; stage A(T1,h0) -> buf1
        load_a8<0>(A0, a0v, a); load_b8<0>(B0, b0v, b);
        STAGE_HT(As, Ab + gA0 + ks + 64, 1, 0);
        __builtin_amdgcn_s_barrier(); LGKM0;
        __builtin_amdgcn_s_setprio(1); mma_q<0, 0>(a, b, acc); __builtin_amdgcn_s_setprio(0);
        __builtin_amdgcn_s_barrier();

        // ---- ph2: q(mh0,nh1); stage A(T1,h1)
        load_b8<1>(B0, b0v, b);
        STAGE_HT(As, Ab + gA1 + ks + 64, 1, 1);
        __builtin_amdgcn_s_barrier(); LGKM0;
        __builtin_amdgcn_s_setprio(1); mma_q<0, 1>(a, b, acc); __builtin_amdgcn_s_setprio(0);
        __builtin_amdgcn_s_barrier();

        // ---- ph3: q(mh1,nh0); stage B(T2,h0) -> buf0 (B(T0) reads done at ph2 end)
        load_a8<1>(A0, a0v, a);
        if (full) STAGE_HT(Bs, Bb + gB0 + ks + 128, 0, 0);
        __builtin_amdgcn_s_barrier(); LGKM0;
        __builtin_amdgcn_s_setprio(1); mma_q<1, 0>(a, b, acc); __builtin_amdgcn_s_setprio(0);
        __builtin_amdgcn_s_barrier();

        // ---- ph4: q(mh1,nh1); stage B(T2,h1); drain A(T1)+stale before ph5
        if (full) STAGE_HT(Bs, Bb + gB1 + ks + 128, 0, 1);
        __builtin_amdgcn_s_barrier(); LGKM0;
        __builtin_amdgcn_s_setprio(1); mma_q<1, 1>(a, b, acc); __builtin_amdgcn_s_setprio(0);
        if (full) { VMCNT4; } else { VMCNT0; }
        __builtin_amdgcn_s_barrier();

        // ---- ph5: q(mh0,nh0) on buf1; stage A(T2,h0) -> buf0 (A(T0) reads done at ph3 end)
        load_a8<0>(A1, a0v, a); load_b8<0>(B1, b0v, b);
        if (full) STAGE_HT(As, Ab + gA0 + ks + 128, 0, 0);
        __builtin_amdgcn_s_barrier(); LGKM0;
        __builtin_amdgcn_s_setprio(1); mma_q<0, 0>(a, b, acc); __builtin_amdgcn_s_setprio(0);
        __builtin_amdgcn_s_barrier();

        // ---- ph6: q(mh0,nh1); stage A(T2,h1)
        load_b8<1>(B1, b0v, b);
        if (full) STAGE_HT(As, Ab + gA1 + ks + 128, 0, 1);
        __builtin_amdgcn_s_barrier(); LGKM0;
        __builtin_amdgcn_s_setprio(1); mma_q<0, 1>(a, b, acc); __builtin_amdgcn_s_setprio(0);
        __builtin_amdgcn_s_barrier();

        // ---- ph7: q(mh1,nh0); stage B(T3,h0) -> buf1 (B(T1) reads done at ph6 end)
        load_a8<1>(A1, a0v, a);
        if (full) STAGE_HT(Bs, Bb + gB0 + ks + 192, 1, 0);
        __builtin_amdgcn_s_barrier(); LGKM0;
        __builtin_amdgcn_s_setprio(1); mma_q<1, 0>(a, b, acc); __builtin_amdgcn_s_setprio(0);
        __builtin_amdgcn_s_barrier();

        // ---- ph8: q(mh1,nh1); stage B(T3,h1); drain A(T2)+B(T2) before next ph1
        if (full) STAGE_HT(Bs, Bb + gB1 + ks + 192, 1, 1);
        __builtin_amdgcn_s_barrier(); LGKM0;
        __builtin_amdgcn_s_setprio(1); mma_q<1, 1>(a, b, acc); __builtin_amdgcn_s_setprio(0);
        if (full) { VMCNT4; }
        __builtin_amdgcn_s_barrier();
    }

    // ---- epilogue (C/D layout: col = lane&15, row = quad*4 + r per 16x16 frag)
    bf* C = (bf*)Cv + (long)bz * sCb;
    #pragma unroll
    for (int j = 0; j < 4; ++j) {
        int n = n0 + wn * 64 + j * 16 + l15;
        float bv = (EPI == EPI_BIAS) ? bias[n] : 0.f;
        #pragma unroll
        for (int i = 0; i < 8; ++i) {
            int mb = m0 + wm * 128 + i * 16 + quad * 4;
            #pragma unroll
            for (int r = 0; r < 4; ++r) {
                float bm = (EPI == EPI_BIASM) ? bias[mb + r] : bv;
                C[(long)(mb + r) * ldC + n] = __float2bfloat16(acc[i][j][r] + bm);
            }
        }
    }
}

// ---------------------------------------------------------------------------
// Transpose-cast: in (nb, R, C) [TI = float or bf16] -> out (nb, C, R) bf16.
// ---------------------------------------------------------------------------
template<typename TI>
__global__ __launch_bounds__(256)
void transpose_cast(const TI* __restrict__ in, bf* __restrict__ outp, int R, int C)
{
    __shared__ float tile[32][33];
    long base = (long)blockIdx.z * R * C;
    int r0 = blockIdx.y * 32, c0 = blockIdx.x * 32;
    int tx = threadIdx.x & 31, ty = threadIdx.x >> 5;
    #pragma unroll
    for (int i = 0; i < 4; ++i)
        tile[ty + 8 * i][tx] = (float)in[base + (long)(r0 + ty + 8 * i) * C + c0 + tx];
    __syncthreads();
    #pragma unroll
    for (int i = 0; i < 4; ++i)
        outp[base + (long)(c0 + ty + 8 * i) * R + r0 + tx] = __float2bfloat16(tile[tx][ty + 8 * i]);
}

// Batched weight cast: W1b4/W2b4[k] = bf16(Wk[layer*DDm]), layer in {1,2}
__global__ __launch_bounds__(256)
void cast_w12(P4 w, bf* __restrict__ w1b4, bf* __restrict__ w2b4)
{
    long i = (long)blockIdx.x * 256 + threadIdx.x;   // over DDm/4
    int layer = blockIdx.y, k = blockIdx.z;
    const float4* src = (const float4*)(w.p[k] + (long)(layer + 1) * DDm);
    ushort4* dst = (ushort4*)((layer ? w2b4 : w1b4) + (long)k * DDm);
    float4 v = src[i];
    ushort4 o; o.x = f2bf_rne(v.x); o.y = f2bf_rne(v.y); o.z = f2bf_rne(v.z); o.w = f2bf_rne(v.w);
    dst[i] = o;
}

// Batched W0 transpose-cast: w0t4[k] = bf16(Wk[0]^T)
__global__ __launch_bounds__(256)
void transpose_w0(P4 w, bf* __restrict__ w0t4)
{
    __shared__ float tile[32][33];
    int k = blockIdx.z;
    const float* in = w.p[k];
    bf* outp = w0t4 + (long)k * DDm;
    int r0 = blockIdx.y * 32, c0 = blockIdx.x * 32;
    int tx = threadIdx.x & 31, ty = threadIdx.x >> 5;
    #pragma unroll
    for (int i = 0; i < 4; ++i)
        tile[ty + 8 * i][tx] = in[(long)(r0 + ty + 8 * i) * Dn + c0 + tx];
    __syncthreads();
    #pragma unroll
    for (int i = 0; i < 4; ++i)
        outp[(long)(c0 + ty + 8 * i) * Dn + r0 + tx] = __float2bfloat16(tile[tx][ty + 8 * i]);
}

// Batched bias compose. stage 0: out4[k]=W1_k*b0_k+b1_k; stage 1: out4[k]=W2_k*vin4[k]+b2_k
__global__ __launch_bounds__(256)
void matvec4(P4 w, P4 b, const float* __restrict__ vin4, float* __restrict__ out4, int stage)
{
    int k = blockIdx.y, o = blockIdx.x;
    const float* W = w.p[k] + (long)(stage ? 2 : 1) * DDm + (long)o * Dn;
    const float* v = stage ? (vin4 + (long)k * Dn) : b.p[k];
    const float* c = b.p[k] + (long)(stage ? 2 : 1) * Dn;
    float s = 0.f;
    for (int i = threadIdx.x; i < Dn; i += 256) s += W[i] * v[i];
    __shared__ float red[256];
    red[threadIdx.x] = s; __syncthreads();
    for (int off = 128; off > 0; off >>= 1) {
        if (threadIdx.x < off) red[threadIdx.x] += red[threadIdx.x + off];
        __syncthreads();
    }
    if (threadIdx.x == 0) out4[(long)k * Dn + o] = red[0] + c[o];
}

// Strided row sum-of-squares (bf16 in, fp32 out), vectorized ushort4.
// row -> b = row / rpb, r = row % rpb; base = b*bstride + r*ld; ncols in {1024,2048}
__global__ __launch_bounds__(256)
void rowsumsq_s(const unsigned short* __restrict__ v, float* __restrict__ outp,
                int ncols, int ld, int rpb, long bstride)
{
    int row = blockIdx.x;
    int b = row / rpb, r = row % rpb;
    const unsigned short* p = v + (long)b * bstride + (long)r * ld;
    float s = 0.f;
    for (int c4 = threadIdx.x * 4; c4 < ncols; c4 += 1024) {
        ushort4 u = *(const ushort4*)(p + c4);
        float a0 = bf2f(u.x), a1 = bf2f(u.y), a2 = bf2f(u.z), a3 = bf2f(u.w);
        s += a0 * a0 + a1 * a1 + a2 * a2 + a3 * a3;
    }
    __shared__ float red[256];
    red[threadIdx.x] = s; __syncthreads();
    for (int off = 128; off > 0; off >>= 1) {
        if (threadIdx.x < off) red[threadIdx.x] += red[threadIdx.x + off];
        __syncthreads();
    }
    if (threadIdx.x == 0) outp[row] = red[0];
}

// ---------------------------------------------------------------------------
// Row softmax, fp32 in (rows x M contiguous) -> bf16 out (channel branch).
// ---------------------------------------------------------------------------
template<int M>
__global__ __launch_bounds__(256)
void softmax_row_bf16(const float* __restrict__ G, bf* __restrict__ outp)
{
    constexpr int NV = M / 1024;    // float4s per thread
    long row = blockIdx.x;
    const float4* p = (const float4*)(G + row * (long)M);
    ushort4* q = (ushort4*)(outp + row * (long)M);
    __shared__ float red[256];

    float4 v[NV];
    float lmax = -3.4e38f;
    #pragma unroll
    for (int k = 0; k < NV; ++k) {
        v[k] = p[threadIdx.x + 256 * k];
        lmax = fmaxf(lmax, fmaxf(fmaxf(v[k].x, v[k].y), fmaxf(v[k].z, v[k].w)));
    }
    red[threadIdx.x] = lmax; __syncthreads();
    for (int off = 128; off > 0; off >>= 1) {
        if (threadIdx.x < off) red[threadIdx.x] = fmaxf(red[threadIdx.x], red[threadIdx.x + off]);
        __syncthreads();
    }
    float mm = red[0]; __syncthreads();

    float s = 0.f;
    #pragma unroll
    for (int k = 0; k < NV; ++k) {
        v[k].x = __expf(v[k].x - mm); v[k].y = __expf(v[k].y - mm);
        v[k].z = __expf(v[k].z - mm); v[k].w = __expf(v[k].w - mm);
        s += (v[k].x + v[k].y) + (v[k].z + v[k].w);
    }
    red[threadIdx.x] = s; __syncthreads();
    for (int off = 128; off > 0; off >>= 1) {
        if (threadIdx.x < off) red[threadIdx.x] += red[threadIdx.x + off];
        __syncthreads();
    }
    float inv = 1.f / red[0];
    #pragma unroll
    for (int k = 0; k < NV; ++k) {
        ushort4 o;
        o.x = f2bf_rne(v[k].x * inv); o.y = f2bf_rne(v[k].y * inv);
        o.z = f2bf_rne(v[k].z * inv); o.w = f2bf_rne(v[k].w * inv);
        q[threadIdx.x + 256 * k] = o;
    }
}

// In-place row softmax on bf16, M = Ln (2048): 8 shorts/thread, one 16B ld/st.
__global__ __launch_bounds__(256)
void softmax_ip_bf16(unsigned short* __restrict__ G)
{
    long row = blockIdx.x;
    s16x8* p = (s16x8*)(G + row * (long)Ln);
    s16x8 raw = p[threadIdx.x];
    float v[8];
    #pragma unroll
    for (int j = 0; j < 8; ++j) v[j] = bf2f((unsigned short)raw[j]);

    __shared__ float red[256];
    float lmax = -3.4e38f;
    #pragma unroll
    for (int j = 0; j < 8; ++j) lmax = fmaxf(lmax, v[j]);
    red[threadIdx.x] = lmax; __syncthreads();
    for (int off = 128; off > 0; off >>= 1) {
        if (threadIdx.x < off) red[threadIdx.x] = fmaxf(red[threadIdx.x], red[threadIdx.x + off]);
        __syncthreads();
    }
    float mm = red[0]; __syncthreads();

    float s = 0.f;
    #pragma unroll
    for (int j = 0; j < 8; ++j) { v[j] = __expf(v[j] - mm); s += v[j]; }
    red[threadIdx.x] = s; __syncthreads();
    for (int off = 128; off > 0; off >>= 1) {
        if (threadIdx.x < off) red[threadIdx.x] += red[threadIdx.x + off];
        __syncthreads();
    }
    float inv = 1.f / red[0];
    s16x8 o;
    #pragma unroll
    for (int j = 0; j < 8; ++j) o[j] = (short)f2bf_rne(v[j] * inv);
    p[threadIdx.x] = o;
}

// In-place square transpose of (nb, Ln, Ln) bf16, 32x32 tile pairs.
__global__ __launch_bounds__(256)
void transpose_ip(unsigned short* __restrict__ G)
{
    int bi = blockIdx.y, bj = blockIdx.x;
    if (bj < bi) return;
    long base = (long)blockIdx.z * LLm;
    __shared__ unsigned short t1[32][33], t2[32][33];
    int tx = threadIdx.x & 31, ty = threadIdx.x >> 5;
    int r0 = bi * 32, c0 = bj * 32;
    #pragma unroll
    for (int i = 0; i < 4; ++i)
        t1[ty + 8 * i][tx] = G[base + (long)(r0 + ty + 8 * i) * Ln + c0 + tx];
    if (bi != bj) {
        #pragma unroll
        for (int i = 0; i < 4; ++i)
            t2[ty + 8 * i][tx] = G[base + (long)(c0 + ty + 8 * i) * Ln + r0 + tx];
    }
    __syncthreads();
    #pragma unroll
    for (int i = 0; i < 4; ++i)
        G[base + (long)(c0 + ty + 8 * i) * Ln + r0 + tx] = t1[tx][ty + 8 * i];
    if (bi != bj) {
        #pragma unroll
        for (int i = 0; i < 4; ++i)
            G[base + (long)(r0 + ty + 8 * i) * Ln + c0 + tx] = t2[tx][ty + 8 * i];
    }
}

// ---------------------------------------------------------------------------
// Host-side GEMM dispatch
// ---------------------------------------------------------------------------
static void glaunch(hipStream_t st, int epi,
                    const bf* A, long sAb, int ldA,
                    const bf* Bt, long sBb, int ldB,
                    void* C, long sCb, int ldC,
                    const float* bias, const float* rowN, const float* colN,
                    const float* resid, long sRb,
                    int M, int N, int K, int nb)
{
    const short* As = (const short*)A;
    const short* Bs = (const short*)Bt;

    // Route big cheap-epilogue GEMMs to the 256x256 8-phase kernel.
    // CAUCHY* stays on the 128^2 kernel: its transcendental epilogue needs
    // multi-block/CU overlap and would spill the 256-reg budget at 8 waves.
    if (!(M % 256) && !(N % 256) && !(K % 128) && (long)(M / 256) * (N / 256) * nb >= 256 &&
        (epi == EPI_BIAS || epi == EPI_BIASM || epi == EPI_PLAIN)) {
        dim3 g8(N / 256, M / 256, nb), blk8(512);
        switch (epi) {
        case EPI_BIAS:  gemm_nt8<EPI_BIAS> <<<g8, blk8, 0, st>>>(As, sAb, ldA, Bs, sBb, ldB, C, sCb, ldC, bias, M, N, K); break;
        case EPI_BIASM: gemm_nt8<EPI_BIASM><<<g8, blk8, 0, st>>>(As, sAb, ldA, Bs, sBb, ldB, C, sCb, ldC, bias, M, N, K); break;
        default:        gemm_nt8<EPI_PLAIN><<<g8, blk8, 0, st>>>(As, sAb, ldA, Bs, sBb, ldB, C, sCb, ldC, bias, M, N, K); break;
        }
        return;
    }

    dim3 g(N / 128, M / 128, nb), blk(256);
    switch (epi) {
    case EPI_BIAS:    gemm_nt<EPI_BIAS>   <<<g, blk, 0, st>>>(As, sAb, ldA, Bs, sBb, ldB, C, sCb, ldC, bias, rowN, colN, resid, sRb, M, N, K); break;
    case EPI_BIASM:   gemm_nt<EPI_BIASM>  <<<g, blk, 0, st>>>(As, sAb, ldA, Bs, sBb, ldB, C, sCb, ldC, bias, rowN, colN, resid, sRb, M, N, K); break;
    case EPI_PLAIN:   gemm_nt<EPI_PLAIN>  <<<g, blk, 0, st>>>(As, sAb, ldA, Bs, sBb, ldB, C, sCb, ldC, bias, rowN, colN, resid, sRb, M, N, K); break;
    case EPI_CAUCHY:  gemm_nt<EPI_CAUCHY> <<<g, blk, 0, st>>>(As, sAb, ldA, Bs, sBb, ldB, C, sCb, ldC, bias, rowN, colN, resid, sRb, M, N, K); break;
    case EPI_CAUCHYB: gemm_nt<EPI_CAUCHYB><<<g, blk, 0, st>>>(As, sAb, ldA, Bs, sBb, ldB, C, sCb, ldC, bias, rowN, colN, resid, sRb, M, N, K); break;
    default:          gemm_nt<EPI_RESID>  <<<g, blk, 0, st>>>(As, sAb, ldA, Bs, sBb, ldB, C, sCb, ldC, bias, rowN, colN, resid, sRb, M, N, K); break;
    }
}

extern "C" void kernel_launch(void* const* d_in, const int* in_sizes, int n_in,
                              void* d_out, int out_size, void* d_ws, size_t ws_size,
                              hipStream_t stream)
{
    const float* x = (const float*)d_in[0];
    float* out = (float*)d_out;

    uint8_t* wsb = (uint8_t*)d_ws;
    if (ws_size < 159600640u) return;

    bf*    x_t    = (bf*)(wsb + 0);
    bf*    dscore = (bf*)(wsb + 33554432);
    bf*    Weff   = (bf*)(wsb + 50331648);
    float* beff   = (float*)(wsb + 58720256);    // 4 x D
    float* b01_4  = (float*)(wsb + 58736640);    // 4 x D
    float* ns_d   = (float*)(wsb + 58753024);
    float* nc_d   = ns_d + (long)Bn * Dn;
    float* ns_l   = nc_d + (long)Bn * Dn;
    float* nc_l   = ns_l + (long)Bn * Ln;
    uint8_t* O1   = wsb + 58937344;              // 67,108,864
    uint8_t* O2   = wsb + 126046208;             // 33,554,432

    // O1 sub-layouts (time-disjoint)
    bf* W1b4 = (bf*)O1;                // compose staging: 5 x 4*DDm shorts = 40MB
    bf* W2b4 = W1b4 + 4 * DDm;
    bf* W0t4 = W1b4 + 8 * DDm;
    bf* Zb4  = W1b4 + 12 * DDm;
    bf* Zt4  = W1b4 + 16 * DDm;
    bf* dsdc = (bf*)O1;                // (B, 2D, L) bf16 = 67MB
    bf* dscoreT = (bf*)O1;             // (B, D, D) bf16 (after dsdc dead)
    bf* lslc = (bf*)O1;                // (B, L, 2D) bf16 = 67MB

    float* GdT = (float*)O2;           // (B, D, D) fp32
    bf*    t1  = (bf*)O2;              // (B, D, L) bf16 (after GdT dead)
    bf*    Gl  = x_t;                  // token phase: 4 x (L, L) bf16 (x_t dead)

    P4 W, Bv;
    for (int k = 0; k < 4; ++k) { W.p[k] = (const float*)d_in[1 + 2 * k]; Bv.p[k] = (const float*)d_in[2 + 2 * k]; }

    // ---- x transpose-cast: (B,D,L) f32 -> (B,L,D) bf16 ----
    transpose_cast<float><<<dim3(Ln / 32, Dn / 32, Bn), 256, 0, stream>>>(x, x_t, Dn, Ln);

    // ---- weight staging (batched) + bias compose ----
    cast_w12<<<dim3((unsigned)(DDm / 4 / 256), 2, 4), 256, 0, stream>>>(W, W1b4, W2b4);
    transpose_w0<<<dim3(Dn / 32, Dn / 32, 4), 256, 0, stream>>>(W, W0t4);
    matvec4<<<dim3(Dn, 4), 256, 0, stream>>>(W, Bv, nullptr, b01_4, 0);
    matvec4<<<dim3(Dn, 4), 256, 0, stream>>>(W, Bv, b01_4, beff, 1);

    // ---- compose Weff = W2*W1*W0 (nb=4 batched) ----
    glaunch(stream, EPI_PLAIN, W1b4, DDm, Dn, W0t4, DDm, Dn, Zb4, DDm, Dn,
            nullptr, nullptr, nullptr, nullptr, 0, Dn, Dn, Dn, 4);
    transpose_cast<bf><<<dim3(Dn / 32, Dn / 32, 4), 256, 0, stream>>>(Zb4, Zt4, Dn, Dn);
    glaunch(stream, EPI_PLAIN, W2b4, DDm, Dn, Zt4, DDm, Dn, Weff, DDm, Dn,
            nullptr, nullptr, nullptr, nullptr, 0, Dn, Dn, Dn, 4);

    // ---- channel branch: dsx||dcx in one concat GEMM (M=2048) ----
    glaunch(stream, EPI_BIASM, Weff, 0, Dn, x_t, DL, Dn, dsdc, 2 * DL, Ln,
            beff, nullptr, nullptr, nullptr, 0, 2 * Dn, Ln, Dn, Bn);

    rowsumsq_s<<<dim3(Bn * Dn), 256, 0, stream>>>((const unsigned short*)dsdc,      ns_d, Ln, Ln, Dn, 2 * DL);
    rowsumsq_s<<<dim3(Bn * Dn), 256, 0, stream>>>((const unsigned short*)(dsdc + DL), nc_d, Ln, Ln, Dn, 2 * DL);

    // GdT fp32 = cauchy(dcx @ dsx^T) (rowN/colN swapped for the transpose)
    glaunch(stream, EPI_CAUCHY, dsdc + DL, 2 * DL, Ln, dsdc, 2 * DL, Ln, GdT, DDm, Dn,
            nullptr, nc_d, ns_d, nullptr, 0, Dn, Dn, Ln, Bn);
    // softmax over original axis 1 == row softmax of GdT -> dscoreT, then transpose
    softmax_row_bf16<Dn><<<dim3(Bn * Dn), 256, 0, stream>>>(GdT, dscoreT);
    transpose_cast<bf><<<dim3(Dn / 32, Dn / 32, Bn), 256, 0, stream>>>(dscoreT, dscore, Dn, Dn);

    // ---- token branch: lsx_t||lcx_t in one concat GEMM (N=2048) ----
    glaunch(stream, EPI_BIAS, x_t, DL, Dn, Weff + 2 * DDm, 0, Dn, lslc, 2 * DL, 2 * Dn,
            beff + 2 * Dn, nullptr, nullptr, nullptr, 0, Ln, 2 * Dn, Dn, Bn);

    rowsumsq_s<<<dim3(Bn * Ln), 256, 0, stream>>>((const unsigned short*)lslc,        ns_l, Dn, 2 * Dn, Ln, 2 * DL);
    rowsumsq_s<<<dim3(Bn * Ln), 256, 0, stream>>>((const unsigned short*)(lslc + Dn), nc_l, Dn, 2 * Dn, Ln, 2 * DL);

    // t1 = dscore @ x, all 8 batches (x_t and dscore dead afterwards)
    glaunch(stream, EPI_PLAIN, dscore, DDm, Dn, x_t, DL, Dn, t1, DL, Ln,
            nullptr, nullptr, nullptr, nullptr, 0, Dn, Ln, Dn, Bn);

    // ---- token score + apply, in 4-batch halves ----
    for (int h = 0; h < 2; ++h) {
        long bo = 4L * h;
        const bf* lsx = lslc + bo * 2 * DL;
        const bf* lcx = lsx + Dn;
        // Gl half bf16 = cauchy(lsx^T @ lcx) (normal layout)
        glaunch(stream, EPI_CAUCHYB, lsx, 2 * DL, 2 * Dn, lcx, 2 * DL, 2 * Dn,
                Gl, LLm, Ln, nullptr, ns_l + bo * Ln, nc_l + bo * Ln, nullptr, 0,
                Ln, Ln, Dn, 4);
        // softmax over axis 2 == row softmax, in place
        softmax_ip_bf16<<<dim3(4 * Ln), 256, 0, stream>>>((unsigned short*)Gl);
        // in-place transpose -> lscore^T (Bt operand)
        transpose_ip<<<dim3(Ln / 32, Ln / 32, 4), 256, 0, stream>>>((unsigned short*)Gl);
        // out = (t1 @ lscore + x) / 2
        glaunch(stream, EPI_RESID, t1 + bo * DL, DL, Ln, Gl, LLm, Ln,
                out + bo * DL, DL, Ln, nullptr, nullptr, nullptr, x + bo * DL, DL,
                Dn, Ln, Ln, 4);
    }
}

// Round 3
// 1047.880 us; speedup vs baseline: 1.3241x; 1.3241x over previous
//
#include <hip/hip_runtime.h>
#include <hip/hip_bf16.h>
#include <math.h>

// Problem constants
static constexpr int  Bn = 8, Dn = 1024, Ln = 2048;
static constexpr long DL  = (long)Dn * Ln;
static constexpr long DDm = (long)Dn * Dn;
static constexpr long LLm = (long)Ln * Ln;
static constexpr float P_EXP = 1.01005016708416805754f; // exp(0.01)
static constexpr float PI_F  = 3.14159265358979323846f;

using bf = __hip_bfloat16;
typedef short s16x8 __attribute__((ext_vector_type(8)));   // 8 bf16 = 4 VGPRs (MFMA A/B frag)
typedef float f32x4 __attribute__((ext_vector_type(4)));   // MFMA C/D frag

#define GPTR(x) ((const __attribute__((address_space(1))) void*)(x))
#define LPTR(x) ((__attribute__((address_space(3))) void*)(x))

enum { EPI_BIAS = 0, EPI_PLAIN = 1, EPI_CAUCHY = 2, EPI_RESID = 3, EPI_BIASM = 4, EPI_CAUCHYB = 5 };

// bf16 RNE pack (finite values only)
static __device__ inline unsigned short f2bf_rne(float f)
{
    union { float f; unsigned u; } uf; uf.f = f;
    unsigned r = uf.u + 0x7fff + ((uf.u >> 16) & 1);
    return (unsigned short)(r >> 16);
}
static __device__ inline float bf2f(unsigned short s)
{
    union { unsigned u; float f; } uf; uf.u = ((unsigned)s) << 16;
    return uf.f;
}

struct P4 { const float* p[4]; };

// ---------------------------------------------------------------------------
// NT bf16 MFMA GEMM: C[b,m,n] = sum_k A[b,m,k] * Bt[b,n,k]   (both k-contig)
// 128x128 tile, BK=32, 256 threads (4 waves, 2x2 of 64x64 wave tiles),
// global_load_lds width-16 staging, swizzled LDS k-chunks.
// launch_bounds(256,4): 4 resident blocks/CU -> epilogue overlaps other
// blocks' K-loops (incl. the transcendental CAUCHY epilogue).
//
// BIAS/BIASM additionally fuse the row sum-of-squares of the *stored bf16*
// values (bit-identical to the old separate rowsumsq_s pass):
//   BIASM (channel concat, M=2Dn): row m -> m<Dn ? rowN[bz*Dn+m] : colN[bz*Dn+m-Dn]
//   BIAS  (token concat,  N=2Dn): row m -> n0<Dn ? rowN[bz*Ln+m] : colN[bz*Ln+m]
// Guarded by rowN != nullptr; per-row partial reduced across the 16 lanes
// sharing a row (shfl_xor 1/2/4/8), one atomicAdd per row per wave.
// ---------------------------------------------------------------------------
template<int EPI>
__global__ __launch_bounds__(256, 4)
void gemm_nt(const short* __restrict__ A, long sAb, int ldA,
             const short* __restrict__ Bt, long sBb, int ldB,
             void* __restrict__ Cv, long sCb, int ldC,
             const float* __restrict__ bias,
             const float* __restrict__ rowN, const float* __restrict__ colN,
             const float* __restrict__ resid, long sRb,
             int M, int N, int K)
{
    __shared__ short As[128 * 32];   // row-major, 32 bf16 per row, k-chunk swizzled
    __shared__ short Bs[128 * 32];

    const int tid  = threadIdx.x;
    const int lane = tid & 63;
    const int w    = tid >> 6;           // wave 0..3
    const int wm   = w >> 1, wn = w & 1; // 2x2 wave grid
    const int m0   = blockIdx.y * 128;
    const int n0   = blockIdx.x * 128;
    const int bz   = blockIdx.z;

    const short* Ab = A  + (long)bz * sAb;
    const short* Bb = Bt + (long)bz * sBb;

    const int srow = lane >> 2;                                  // 0..15 row within 16-row chunk
    const int kc   = ((lane & 3) + 4 - ((lane >> 3) & 3)) & 3;   // swizzled global k-chunk
    const int quad = lane >> 4;
    const int l15  = lane & 15;

    // LDS read offsets (shorts) for the 4 A / 4 B fragments
    int aoff[4], boff[4];
    #pragma unroll
    for (int i = 0; i < 4; ++i) {
        int rA = wm * 64 + i * 16 + l15;
        aoff[i] = rA * 32 + (((quad + (rA >> 1)) & 3) << 3);
        int rB = wn * 64 + i * 16 + l15;
        boff[i] = rB * 32 + (((quad + (rB >> 1)) & 3) << 3);
    }

    // staging: wave w owns 1KB chunks {2w, 2w+1} of both A and B tiles
    const int  ca0 = 2 * w;
    const long gA0 = (long)(m0 + ca0 * 16 + srow)       * ldA + kc * 8;
    const long gA1 = (long)(m0 + (ca0 + 1) * 16 + srow) * ldA + kc * 8;
    const long gB0 = (long)(n0 + ca0 * 16 + srow)       * ldB + kc * 8;
    const long gB1 = (long)(n0 + (ca0 + 1) * 16 + srow) * ldB + kc * 8;
    short* lA0 = As + ca0 * 512;
    short* lA1 = As + ca0 * 512 + 512;
    short* lB0 = Bs + ca0 * 512;
    short* lB1 = Bs + ca0 * 512 + 512;

    f32x4 acc[4][4] = {};

    for (int k0 = 0; k0 < K; k0 += 32) {
        __builtin_amdgcn_global_load_lds(GPTR(Ab + gA0 + k0), LPTR(lA0), 16, 0, 0);
        __builtin_amdgcn_global_load_lds(GPTR(Ab + gA1 + k0), LPTR(lA1), 16, 0, 0);
        __builtin_amdgcn_global_load_lds(GPTR(Bb + gB0 + k0), LPTR(lB0), 16, 0, 0);
        __builtin_amdgcn_global_load_lds(GPTR(Bb + gB1 + k0), LPTR(lB1), 16, 0, 0);
        __syncthreads();

        s16x8 af[4], bfr[4];
        #pragma unroll
        for (int i = 0; i < 4; ++i) af[i]  = *(const s16x8*)(As + aoff[i]);
        #pragma unroll
        for (int j = 0; j < 4; ++j) bfr[j] = *(const s16x8*)(Bs + boff[j]);
        #pragma unroll
        for (int i = 0; i < 4; ++i)
            #pragma unroll
            for (int j = 0; j < 4; ++j)
                acc[i][j] = __builtin_amdgcn_mfma_f32_16x16x32_bf16(af[i], bfr[j], acc[i][j], 0, 0, 0);
        __syncthreads();
    }

    // Epilogue. C/D layout: col = lane&15, row = quad*4 + r within each 16x16.
    if constexpr (EPI == EPI_BIAS || EPI == EPI_PLAIN || EPI == EPI_BIASM) {
        bf* C = (bf*)Cv + (long)bz * sCb;
        #pragma unroll
        for (int i = 0; i < 4; ++i) {
            int mb = m0 + wm * 64 + i * 16 + quad * 4;
            #pragma unroll
            for (int r = 0; r < 4; ++r) {
                float s = 0.f;
                #pragma unroll
                for (int j = 0; j < 4; ++j) {
                    int n = n0 + wn * 64 + j * 16 + l15;
                    float bmv = (EPI == EPI_BIAS) ? bias[n]
                              : (EPI == EPI_BIASM) ? bias[mb + r] : 0.f;
                    bf hv = __float2bfloat16(acc[i][j][r] + bmv);
                    C[(long)(mb + r) * ldC + n] = hv;
                    if constexpr (EPI == EPI_BIAS || EPI == EPI_BIASM) {
                        float q = bf2f(*reinterpret_cast<unsigned short*>(&hv));
                        s += q * q;
                    }
                }
                if constexpr (EPI == EPI_BIAS || EPI == EPI_BIASM) {
                    if (rowN) {
                        s += __shfl_xor(s, 1);
                        s += __shfl_xor(s, 2);
                        s += __shfl_xor(s, 4);
                        s += __shfl_xor(s, 8);
                        if (l15 == 0) {
                            int m = mb + r;
                            float* dst;
                            if constexpr (EPI == EPI_BIASM)   // split by output row half
                                dst = (m < Dn) ? ((float*)rowN + (long)bz * Dn + m)
                                               : ((float*)colN + (long)bz * Dn + (m - Dn));
                            else                              // split by output col half
                                dst = (n0 < Dn) ? ((float*)rowN + (long)bz * Ln + m)
                                                : ((float*)colN + (long)bz * Ln + m);
                            atomicAdd(dst, s);
                        }
                    }
                }
            }
        }
    } else if constexpr (EPI == EPI_CAUCHY || EPI == EPI_CAUCHYB) {
        const float* rN = rowN + (long)bz * M;
        const float* cN = colN + (long)bz * N;
        #pragma unroll
        for (int j = 0; j < 4; ++j) {
            int n = n0 + wn * 64 + j * 16 + l15;
            float cn = cN[n];
            #pragma unroll
            for (int i = 0; i < 4; ++i) {
                int mb = m0 + wm * 64 + i * 16 + quad * 4;
                #pragma unroll
                for (int r = 0; r < 4; ++r) {
                    int m = mb + r;
                    float g = acc[i][j][r];
                    float ratio = (g * g) / (rN[m] * cn);
                    float o = __powf(ratio, P_EXP) - ((m == n) ? 1.f : 0.f);
                    float v = fmaxf(0.5f - 0.5f * __cosf(PI_F * o), 0.f);
                    if constexpr (EPI == EPI_CAUCHY)
                        ((float*)Cv + (long)bz * sCb)[(long)m * ldC + n] = v;
                    else
                        ((unsigned short*)Cv + (long)bz * sCb)[(long)m * ldC + n] = f2bf_rne(v);
                }
            }
        }
    } else { // EPI_RESID
        float* C = (float*)Cv + (long)bz * sCb;
        const float* Rs = resid + (long)bz * sRb;
        #pragma unroll
        for (int j = 0; j < 4; ++j) {
            int n = n0 + wn * 64 + j * 16 + l15;
            #pragma unroll
            for (int i = 0; i < 4; ++i) {
                int mb = m0 + wm * 64 + i * 16 + quad * 4;
                #pragma unroll
                for (int r = 0; r < 4; ++r) {
                    int m = mb + r;
                    C[(long)m * ldC + n] = (acc[i][j][r] + Rs[(long)m * ldC + n]) * 0.5f;
                }
            }
        }
    }
}

// Zero-init for the fused norm accumulators (contiguous 49152 floats).
__global__ __launch_bounds__(256)
void zero_f4(float4* __restrict__ p)
{
    p[(long)blockIdx.x * 256 + threadIdx.x] = float4{0.f, 0.f, 0.f, 0.f};
}

// ---------------------------------------------------------------------------
// Transpose-cast: in (nb, R, C) [TI = float or bf16] -> out (nb, C, R) bf16.
// ---------------------------------------------------------------------------
template<typename TI>
__global__ __launch_bounds__(256)
void transpose_cast(const TI* __restrict__ in, bf* __restrict__ outp, int R, int C)
{
    __shared__ float tile[32][33];
    long base = (long)blockIdx.z * R * C;
    int r0 = blockIdx.y * 32, c0 = blockIdx.x * 32;
    int tx = threadIdx.x & 31, ty = threadIdx.x >> 5;
    #pragma unroll
    for (int i = 0; i < 4; ++i)
        tile[ty + 8 * i][tx] = (float)in[base + (long)(r0 + ty + 8 * i) * C + c0 + tx];
    __syncthreads();
    #pragma unroll
    for (int i = 0; i < 4; ++i)
        outp[base + (long)(c0 + ty + 8 * i) * R + r0 + tx] = __float2bfloat16(tile[tx][ty + 8 * i]);
}

// Batched weight cast: W1b4/W2b4[k] = bf16(Wk[layer*DDm]), layer in {1,2}
__global__ __launch_bounds__(256)
void cast_w12(P4 w, bf* __restrict__ w1b4, bf* __restrict__ w2b4)
{
    long i = (long)blockIdx.x * 256 + threadIdx.x;   // over DDm/4
    int layer = blockIdx.y, k = blockIdx.z;
    const float4* src = (const float4*)(w.p[k] + (long)(layer + 1) * DDm);
    ushort4* dst = (ushort4*)((layer ? w2b4 : w1b4) + (long)k * DDm);
    float4 v = src[i];
    ushort4 o; o.x = f2bf_rne(v.x); o.y = f2bf_rne(v.y); o.z = f2bf_rne(v.z); o.w = f2bf_rne(v.w);
    dst[i] = o;
}

// Batched W0 transpose-cast: w0t4[k] = bf16(Wk[0]^T)
__global__ __launch_bounds__(256)
void transpose_w0(P4 w, bf* __restrict__ w0t4)
{
    __shared__ float tile[32][33];
    int k = blockIdx.z;
    const float* in = w.p[k];
    bf* outp = w0t4 + (long)k * DDm;
    int r0 = blockIdx.y * 32, c0 = blockIdx.x * 32;
    int tx = threadIdx.x & 31, ty = threadIdx.x >> 5;
    #pragma unroll
    for (int i = 0; i < 4; ++i)
        tile[ty + 8 * i][tx] = in[(long)(r0 + ty + 8 * i) * Dn + c0 + tx];
    __syncthreads();
    #pragma unroll
    for (int i = 0; i < 4; ++i)
        outp[(long)(c0 + ty + 8 * i) * Dn + r0 + tx] = __float2bfloat16(tile[tx][ty + 8 * i]);
}

// Batched bias compose. stage 0: out4[k]=W1_k*b0_k+b1_k; stage 1: out4[k]=W2_k*vin4[k]+b2_k
__global__ __launch_bounds__(256)
void matvec4(P4 w, P4 b, const float* __restrict__ vin4, float* __restrict__ out4, int stage)
{
    int k = blockIdx.y, o = blockIdx.x;
    const float* W = w.p[k] + (long)(stage ? 2 : 1) * DDm + (long)o * Dn;
    const float* v = stage ? (vin4 + (long)k * Dn) : b.p[k];
    const float* c = b.p[k] + (long)(stage ? 2 : 1) * Dn;
    float s = 0.f;
    for (int i = threadIdx.x; i < Dn; i += 256) s += W[i] * v[i];
    __shared__ float red[256];
    red[threadIdx.x] = s; __syncthreads();
    for (int off = 128; off > 0; off >>= 1) {
        if (threadIdx.x < off) red[threadIdx.x] += red[threadIdx.x + off];
        __syncthreads();
    }
    if (threadIdx.x == 0) out4[(long)k * Dn + o] = red[0] + c[o];
}

// ---------------------------------------------------------------------------
// Row softmax, fp32 in (rows x M contiguous) -> bf16 out (channel branch).
// ---------------------------------------------------------------------------
template<int M>
__global__ __launch_bounds__(256)
void softmax_row_bf16(const float* __restrict__ G, bf* __restrict__ outp)
{
    constexpr int NV = M / 1024;    // float4s per thread
    long row = blockIdx.x;
    const float4* p = (const float4*)(G + row * (long)M);
    ushort4* q = (ushort4*)(outp + row * (long)M);
    __shared__ float red[256];

    float4 v[NV];
    float lmax = -3.4e38f;
    #pragma unroll
    for (int k = 0; k < NV; ++k) {
        v[k] = p[threadIdx.x + 256 * k];
        lmax = fmaxf(lmax, fmaxf(fmaxf(v[k].x, v[k].y), fmaxf(v[k].z, v[k].w)));
    }
    red[threadIdx.x] = lmax; __syncthreads();
    for (int off = 128; off > 0; off >>= 1) {
        if (threadIdx.x < off) red[threadIdx.x] = fmaxf(red[threadIdx.x], red[threadIdx.x + off]);
        __syncthreads();
    }
    float mm = red[0]; __syncthreads();

    float s = 0.f;
    #pragma unroll
    for (int k = 0; k < NV; ++k) {
        v[k].x = __expf(v[k].x - mm); v[k].y = __expf(v[k].y - mm);
        v[k].z = __expf(v[k].z - mm); v[k].w = __expf(v[k].w - mm);
        s += (v[k].x + v[k].y) + (v[k].z + v[k].w);
    }
    red[threadIdx.x] = s; __syncthreads();
    for (int off = 128; off > 0; off >>= 1) {
        if (threadIdx.x < off) red[threadIdx.x] += red[threadIdx.x + off];
        __syncthreads();
    }
    float inv = 1.f / red[0];
    #pragma unroll
    for (int k = 0; k < NV; ++k) {
        ushort4 o;
        o.x = f2bf_rne(v[k].x * inv); o.y = f2bf_rne(v[k].y * inv);
        o.z = f2bf_rne(v[k].z * inv); o.w = f2bf_rne(v[k].w * inv);
        q[threadIdx.x + 256 * k] = o;
    }
}

// In-place row softmax on bf16, M = Ln (2048): 8 shorts/thread, one 16B ld/st.
__global__ __launch_bounds__(256)
void softmax_ip_bf16(unsigned short* __restrict__ G)
{
    long row = blockIdx.x;
    s16x8* p = (s16x8*)(G + row * (long)Ln);
    s16x8 raw = p[threadIdx.x];
    float v[8];
    #pragma unroll
    for (int j = 0; j < 8; ++j) v[j] = bf2f((unsigned short)raw[j]);

    __shared__ float red[256];
    float lmax = -3.4e38f;
    #pragma unroll
    for (int j = 0; j < 8; ++j) lmax = fmaxf(lmax, v[j]);
    red[threadIdx.x] = lmax; __syncthreads();
    for (int off = 128; off > 0; off >>= 1) {
        if (threadIdx.x < off) red[threadIdx.x] = fmaxf(red[threadIdx.x], red[threadIdx.x + off]);
        __syncthreads();
    }
    float mm = red[0]; __syncthreads();

    float s = 0.f;
    #pragma unroll
    for (int j = 0; j < 8; ++j) { v[j] = __expf(v[j] - mm); s += v[j]; }
    red[threadIdx.x] = s; __syncthreads();
    for (int off = 128; off > 0; off >>= 1) {
        if (threadIdx.x < off) red[threadIdx.x] += red[threadIdx.x + off];
        __syncthreads();
    }
    float inv = 1.f / red[0];
    s16x8 o;
    #pragma unroll
    for (int j = 0; j < 8; ++j) o[j] = (short)f2bf_rne(v[j] * inv);
    p[threadIdx.x] = o;
}

// In-place square transpose of (nb, Ln, Ln) bf16, 32x32 tile pairs.
__global__ __launch_bounds__(256)
void transpose_ip(unsigned short* __restrict__ G)
{
    int bi = blockIdx.y, bj = blockIdx.x;
    if (bj < bi) return;
    long base = (long)blockIdx.z * LLm;
    __shared__ unsigned short t1[32][33], t2[32][33];
    int tx = threadIdx.x & 31, ty = threadIdx.x >> 5;
    int r0 = bi * 32, c0 = bj * 32;
    #pragma unroll
    for (int i = 0; i < 4; ++i)
        t1[ty + 8 * i][tx] = G[base + (long)(r0 + ty + 8 * i) * Ln + c0 + tx];
    if (bi != bj) {
        #pragma unroll
        for (int i = 0; i < 4; ++i)
            t2[ty + 8 * i][tx] = G[base + (long)(c0 + ty + 8 * i) * Ln + r0 + tx];
    }
    __syncthreads();
    #pragma unroll
    for (int i = 0; i < 4; ++i)
        G[base + (long)(c0 + ty + 8 * i) * Ln + r0 + tx] = t1[tx][ty + 8 * i];
    if (bi != bj) {
        #pragma unroll
        for (int i = 0; i < 4; ++i)
            G[base + (long)(r0 + ty + 8 * i) * Ln + c0 + tx] = t2[tx][ty + 8 * i];
    }
}

// ---------------------------------------------------------------------------
// Host-side GEMM dispatch
// ---------------------------------------------------------------------------
static void glaunch(hipStream_t st, int epi,
                    const bf* A, long sAb, int ldA,
                    const bf* Bt, long sBb, int ldB,
                    void* C, long sCb, int ldC,
                    const float* bias, const float* rowN, const float* colN,
                    const float* resid, long sRb,
                    int M, int N, int K, int nb)
{
    dim3 g(N / 128, M / 128, nb), blk(256);
    const short* As = (const short*)A;
    const short* Bs = (const short*)Bt;
    switch (epi) {
    case EPI_BIAS:    gemm_nt<EPI_BIAS>   <<<g, blk, 0, st>>>(As, sAb, ldA, Bs, sBb, ldB, C, sCb, ldC, bias, rowN, colN, resid, sRb, M, N, K); break;
    case EPI_BIASM:   gemm_nt<EPI_BIASM>  <<<g, blk, 0, st>>>(As, sAb, ldA, Bs, sBb, ldB, C, sCb, ldC, bias, rowN, colN, resid, sRb, M, N, K); break;
    case EPI_PLAIN:   gemm_nt<EPI_PLAIN>  <<<g, blk, 0, st>>>(As, sAb, ldA, Bs, sBb, ldB, C, sCb, ldC, bias, rowN, colN, resid, sRb, M, N, K); break;
    case EPI_CAUCHY:  gemm_nt<EPI_CAUCHY> <<<g, blk, 0, st>>>(As, sAb, ldA, Bs, sBb, ldB, C, sCb, ldC, bias, rowN, colN, resid, sRb, M, N, K); break;
    case EPI_CAUCHYB: gemm_nt<EPI_CAUCHYB><<<g, blk, 0, st>>>(As, sAb, ldA, Bs, sBb, ldB, C, sCb, ldC, bias, rowN, colN, resid, sRb, M, N, K); break;
    default:          gemm_nt<EPI_RESID>  <<<g, blk, 0, st>>>(As, sAb, ldA, Bs, sBb, ldB, C, sCb, ldC, bias, rowN, colN, resid, sRb, M, N, K); break;
    }
}

extern "C" void kernel_launch(void* const* d_in, const int* in_sizes, int n_in,
                              void* d_out, int out_size, void* d_ws, size_t ws_size,
                              hipStream_t stream)
{
    const float* x = (const float*)d_in[0];
    float* out = (float*)d_out;

    // Arena (bytes), total 159,600,640:
    //   x_t   [0,          33,554,432)  (B,L,D) bf16; token phase: Gl half (4 x L x L bf16)
    //   dscore[33,554,432, 50,331,648)  (B,D,D) bf16
    //   Weff  [50,331,648, 58,720,256)  4 x (D,D) bf16
    //   beff  [58,720,256, +16K) b01_4 [+16K, +32K) norms [58,753,024, +192K)
    //   O1    [58,937,344, 126,046,208) 67MB: compose staging / dsdc concat / dscoreT / lslc concat
    //   O2    [126,046,208,159,600,640) 33.5MB: GdT fp32 / t1 bf16
    uint8_t* wsb = (uint8_t*)d_ws;
    if (ws_size < 159600640u) return;

    bf*    x_t    = (bf*)(wsb + 0);
    bf*    dscore = (bf*)(wsb + 33554432);
    bf*    Weff   = (bf*)(wsb + 50331648);
    float* beff   = (float*)(wsb + 58720256);    // 4 x D
    float* b01_4  = (float*)(wsb + 58736640);    // 4 x D
    float* ns_d   = (float*)(wsb + 58753024);
    float* nc_d   = ns_d + (long)Bn * Dn;
    float* ns_l   = nc_d + (long)Bn * Dn;
    float* nc_l   = ns_l + (long)Bn * Ln;
    uint8_t* O1   = wsb + 58937344;              // 67,108,864
    uint8_t* O2   = wsb + 126046208;             // 33,554,432

    // O1 sub-layouts (time-disjoint)
    bf* W1b4 = (bf*)O1;                // compose staging: 5 x 4*DDm shorts = 40MB
    bf* W2b4 = W1b4 + 4 * DDm;
    bf* W0t4 = W1b4 + 8 * DDm;
    bf* Zb4  = W1b4 + 12 * DDm;
    bf* Zt4  = W1b4 + 16 * DDm;
    bf* dsdc = (bf*)O1;                // (B, 2D, L) bf16 = 67MB
    bf* dscoreT = (bf*)O1;             // (B, D, D) bf16 (after dsdc dead)
    bf* lslc = (bf*)O1;                // (B, L, 2D) bf16 = 67MB

    float* GdT = (float*)O2;           // (B, D, D) fp32
    bf*    t1  = (bf*)O2;              // (B, D, L) bf16 (after GdT dead)
    bf*    Gl  = x_t;                  // token phase: 4 x (L, L) bf16 (x_t dead)

    P4 W, Bv;
    for (int k = 0; k < 4; ++k) { W.p[k] = (const float*)d_in[1 + 2 * k]; Bv.p[k] = (const float*)d_in[2 + 2 * k]; }

    // ---- x transpose-cast: (B,D,L) f32 -> (B,L,D) bf16 ----
    transpose_cast<float><<<dim3(Ln / 32, Dn / 32, Bn), 256, 0, stream>>>(x, x_t, Dn, Ln);

    // ---- zero the fused norm accumulators (49152 floats contiguous) ----
    zero_f4<<<dim3(48), 256, 0, stream>>>((float4*)ns_d);

    // ---- weight staging (batched) + bias compose ----
    cast_w12<<<dim3((unsigned)(DDm / 4 / 256), 2, 4), 256, 0, stream>>>(W, W1b4, W2b4);
    transpose_w0<<<dim3(Dn / 32, Dn / 32, 4), 256, 0, stream>>>(W, W0t4);
    matvec4<<<dim3(Dn, 4), 256, 0, stream>>>(W, Bv, nullptr, b01_4, 0);
    matvec4<<<dim3(Dn, 4), 256, 0, stream>>>(W, Bv, b01_4, beff, 1);

    // ---- compose Weff = W2*W1*W0 (nb=4 batched) ----
    glaunch(stream, EPI_PLAIN, W1b4, DDm, Dn, W0t4, DDm, Dn, Zb4, DDm, Dn,
            nullptr, nullptr, nullptr, nullptr, 0, Dn, Dn, Dn, 4);
    transpose_cast<bf><<<dim3(Dn / 32, Dn / 32, 4), 256, 0, stream>>>(Zb4, Zt4, Dn, Dn);
    glaunch(stream, EPI_PLAIN, W2b4, DDm, Dn, Zt4, DDm, Dn, Weff, DDm, Dn,
            nullptr, nullptr, nullptr, nullptr, 0, Dn, Dn, Dn, 4);

    // ---- channel branch: dsx||dcx in one concat GEMM (M=2048, 2048 blocks)
    //      with fused row sum-of-squares -> ns_d / nc_d ----
    glaunch(stream, EPI_BIASM, Weff, 0, Dn, x_t, DL, Dn, dsdc, 2 * DL, Ln,
            beff, ns_d, nc_d, nullptr, 0, 2 * Dn, Ln, Dn, Bn);

    // GdT fp32 = cauchy(dcx @ dsx^T) (rowN/colN swapped for the transpose)
    glaunch(stream, EPI_CAUCHY, dsdc + DL, 2 * DL, Ln, dsdc, 2 * DL, Ln, GdT, DDm, Dn,
            nullptr, nc_d, ns_d, nullptr, 0, Dn, Dn, Ln, Bn);
    // softmax over original axis 1 == row softmax of GdT -> dscoreT, then transpose
    softmax_row_bf16<Dn><<<dim3(Bn * Dn), 256, 0, stream>>>(GdT, dscoreT);
    transpose_cast<bf><<<dim3(Dn / 32, Dn / 32, Bn), 256, 0, stream>>>(dscoreT, dscore, Dn, Dn);

    // ---- token branch: lsx_t||lcx_t in one concat GEMM (N=2048, 2048 blocks)
    //      with fused row sum-of-squares -> ns_l / nc_l ----
    glaunch(stream, EPI_BIAS, x_t, DL, Dn, Weff + 2 * DDm, 0, Dn, lslc, 2 * DL, 2 * Dn,
            beff + 2 * Dn, ns_l, nc_l, nullptr, 0, Ln, 2 * Dn, Dn, Bn);

    // t1 = dscore @ x, all 8 batches (x_t and dscore dead afterwards)
    glaunch(stream, EPI_PLAIN, dscore, DDm, Dn, x_t, DL, Dn, t1, DL, Ln,
            nullptr, nullptr, nullptr, nullptr, 0, Dn, Ln, Dn, Bn);

    // ---- token score + apply, in 4-batch halves ----
    for (int h = 0; h < 2; ++h) {
        long bo = 4L * h;
        const bf* lsx = lslc + bo * 2 * DL;
        const bf* lcx = lsx + Dn;
        // Gl half bf16 = cauchy(lsx^T @ lcx) (normal layout), 1024 blocks
        glaunch(stream, EPI_CAUCHYB, lsx, 2 * DL, 2 * Dn, lcx, 2 * DL, 2 * Dn,
                Gl, LLm, Ln, nullptr, ns_l + bo * Ln, nc_l + bo * Ln, nullptr, 0,
                Ln, Ln, Dn, 4);
        // softmax over axis 2 == row softmax, in place
        softmax_ip_bf16<<<dim3(4 * Ln), 256, 0, stream>>>((unsigned short*)Gl);
        // in-place transpose -> lscore^T (Bt operand)
        transpose_ip<<<dim3(Ln / 32, Ln / 32, 4), 256, 0, stream>>>((unsigned short*)Gl);
        // out = (t1 @ lscore + x) / 2, 512 blocks
        glaunch(stream, EPI_RESID, t1 + bo * DL, DL, Ln, Gl, LLm, Ln,
                out + bo * DL, DL, Ln, nullptr, nullptr, nullptr, x + bo * DL, DL,
                Dn, Ln, Ln, 4);
    }
}

// Round 4
// 1003.443 us; speedup vs baseline: 1.3827x; 1.0443x over previous
//
#include <hip/hip_runtime.h>
#include <hip/hip_bf16.h>
#include <math.h>

// Problem constants
static constexpr int  Bn = 8, Dn = 1024, Ln = 2048;
static constexpr long DL  = (long)Dn * Ln;
static constexpr long DDm = (long)Dn * Dn;
static constexpr long LLm = (long)Ln * Ln;
static constexpr float P_EXP = 1.01005016708416805754f; // exp(0.01)
static constexpr float PI_F  = 3.14159265358979323846f;

using bf = __hip_bfloat16;
typedef short s16x8 __attribute__((ext_vector_type(8)));   // 8 bf16 = 4 VGPRs (MFMA A/B frag)
typedef float f32x4 __attribute__((ext_vector_type(4)));   // MFMA C/D frag

#define GPTR(x) ((const __attribute__((address_space(1))) void*)(x))
#define LPTR(x) ((__attribute__((address_space(3))) void*)(x))

enum { EPI_BIAS = 0, EPI_PLAIN = 1, EPI_RESID = 3, EPI_BIASM = 4, EPI_CAUCHYB = 5 };

// bf16 RNE pack (finite values only)
static __device__ inline unsigned short f2bf_rne(float f)
{
    union { float f; unsigned u; } uf; uf.f = f;
    unsigned r = uf.u + 0x7fff + ((uf.u >> 16) & 1);
    return (unsigned short)(r >> 16);
}
static __device__ inline float bf2f(unsigned short s)
{
    union { unsigned u; float f; } uf; uf.u = ((unsigned)s) << 16;
    return uf.f;
}

struct P4 { const float* p[4]; };

// ---------------------------------------------------------------------------
// NT bf16 MFMA GEMM: C[b,m,n] = sum_k A[b,m,k] * Bt[b,n,k]   (both k-contig)
// 128x128 tile, BK=32, 256 threads (4 waves, 2x2 of 64x64 wave tiles),
// global_load_lds width-16 staging, swizzled LDS k-chunks.
// launch_bounds(256,4): 4 resident blocks/CU -> epilogue overlaps other
// blocks' K-loops (incl. the transcendental CAUCHYB epilogue).
//
// Fused epilogues:
//  BIAS/BIASM: store bf16(acc+bias) and accumulate per-row sum-of-squares of
//    the STORED values into rowN/colN (split by half) via shfl+atomicAdd.
//  CAUCHYB: v = relu(0.5-0.5cos(pi*((g^2/(rN*cN))^P - diag))) in [0,1];
//    store bf16(exp(v)) and accumulate per-row sum of the STORED values into
//    Z (passed via `resid`). Softmax = stored/Z applied later during the
//    transpose pass (exp is monotone-safe: v in [0,1] => e in [1, 2.72]).
// ---------------------------------------------------------------------------
template<int EPI>
__global__ __launch_bounds__(256, 4)
void gemm_nt(const short* __restrict__ A, long sAb, int ldA,
             const short* __restrict__ Bt, long sBb, int ldB,
             void* __restrict__ Cv, long sCb, int ldC,
             const float* __restrict__ bias,
             const float* __restrict__ rowN, const float* __restrict__ colN,
             const float* __restrict__ resid, long sRb,
             int M, int N, int K)
{
    __shared__ short As[128 * 32];   // row-major, 32 bf16 per row, k-chunk swizzled
    __shared__ short Bs[128 * 32];

    const int tid  = threadIdx.x;
    const int lane = tid & 63;
    const int w    = tid >> 6;           // wave 0..3
    const int wm   = w >> 1, wn = w & 1; // 2x2 wave grid
    const int m0   = blockIdx.y * 128;
    const int n0   = blockIdx.x * 128;
    const int bz   = blockIdx.z;

    const short* Ab = A  + (long)bz * sAb;
    const short* Bb = Bt + (long)bz * sBb;

    const int srow = lane >> 2;                                  // 0..15 row within 16-row chunk
    const int kc   = ((lane & 3) + 4 - ((lane >> 3) & 3)) & 3;   // swizzled global k-chunk
    const int quad = lane >> 4;
    const int l15  = lane & 15;

    // LDS read offsets (shorts) for the 4 A / 4 B fragments
    int aoff[4], boff[4];
    #pragma unroll
    for (int i = 0; i < 4; ++i) {
        int rA = wm * 64 + i * 16 + l15;
        aoff[i] = rA * 32 + (((quad + (rA >> 1)) & 3) << 3);
        int rB = wn * 64 + i * 16 + l15;
        boff[i] = rB * 32 + (((quad + (rB >> 1)) & 3) << 3);
    }

    // staging: wave w owns 1KB chunks {2w, 2w+1} of both A and B tiles
    const int  ca0 = 2 * w;
    const long gA0 = (long)(m0 + ca0 * 16 + srow)       * ldA + kc * 8;
    const long gA1 = (long)(m0 + (ca0 + 1) * 16 + srow) * ldA + kc * 8;
    const long gB0 = (long)(n0 + ca0 * 16 + srow)       * ldB + kc * 8;
    const long gB1 = (long)(n0 + (ca0 + 1) * 16 + srow) * ldB + kc * 8;
    short* lA0 = As + ca0 * 512;
    short* lA1 = As + ca0 * 512 + 512;
    short* lB0 = Bs + ca0 * 512;
    short* lB1 = Bs + ca0 * 512 + 512;

    f32x4 acc[4][4] = {};

    for (int k0 = 0; k0 < K; k0 += 32) {
        __builtin_amdgcn_global_load_lds(GPTR(Ab + gA0 + k0), LPTR(lA0), 16, 0, 0);
        __builtin_amdgcn_global_load_lds(GPTR(Ab + gA1 + k0), LPTR(lA1), 16, 0, 0);
        __builtin_amdgcn_global_load_lds(GPTR(Bb + gB0 + k0), LPTR(lB0), 16, 0, 0);
        __builtin_amdgcn_global_load_lds(GPTR(Bb + gB1 + k0), LPTR(lB1), 16, 0, 0);
        __syncthreads();

        s16x8 af[4], bfr[4];
        #pragma unroll
        for (int i = 0; i < 4; ++i) af[i]  = *(const s16x8*)(As + aoff[i]);
        #pragma unroll
        for (int j = 0; j < 4; ++j) bfr[j] = *(const s16x8*)(Bs + boff[j]);
        #pragma unroll
        for (int i = 0; i < 4; ++i)
            #pragma unroll
            for (int j = 0; j < 4; ++j)
                acc[i][j] = __builtin_amdgcn_mfma_f32_16x16x32_bf16(af[i], bfr[j], acc[i][j], 0, 0, 0);
        __syncthreads();
    }

    // Epilogue. C/D layout: col = lane&15, row = quad*4 + r within each 16x16.
    if constexpr (EPI == EPI_BIAS || EPI == EPI_PLAIN || EPI == EPI_BIASM) {
        bf* C = (bf*)Cv + (long)bz * sCb;
        #pragma unroll
        for (int i = 0; i < 4; ++i) {
            int mb = m0 + wm * 64 + i * 16 + quad * 4;
            #pragma unroll
            for (int r = 0; r < 4; ++r) {
                float s = 0.f;
                #pragma unroll
                for (int j = 0; j < 4; ++j) {
                    int n = n0 + wn * 64 + j * 16 + l15;
                    float bmv = (EPI == EPI_BIAS) ? bias[n]
                              : (EPI == EPI_BIASM) ? bias[mb + r] : 0.f;
                    bf hv = __float2bfloat16(acc[i][j][r] + bmv);
                    C[(long)(mb + r) * ldC + n] = hv;
                    if constexpr (EPI == EPI_BIAS || EPI == EPI_BIASM) {
                        float q = bf2f(*reinterpret_cast<unsigned short*>(&hv));
                        s += q * q;
                    }
                }
                if constexpr (EPI == EPI_BIAS || EPI == EPI_BIASM) {
                    if (rowN) {
                        s += __shfl_xor(s, 1);
                        s += __shfl_xor(s, 2);
                        s += __shfl_xor(s, 4);
                        s += __shfl_xor(s, 8);
                        if (l15 == 0) {
                            int m = mb + r;
                            float* dst;
                            if constexpr (EPI == EPI_BIASM)   // split by output row half
                                dst = (m < Dn) ? ((float*)rowN + (long)bz * Dn + m)
                                               : ((float*)colN + (long)bz * Dn + (m - Dn));
                            else                              // split by output col half
                                dst = (n0 < Dn) ? ((float*)rowN + (long)bz * Ln + m)
                                                : ((float*)colN + (long)bz * Ln + m);
                            atomicAdd(dst, s);
                        }
                    }
                }
            }
        }
    } else if constexpr (EPI == EPI_CAUCHYB) {
        const float* rN = rowN + (long)bz * M;
        const float* cN = colN + (long)bz * N;
        float* Zp = (float*)resid + (long)bz * M;
        unsigned short* C = (unsigned short*)Cv + (long)bz * sCb;
        float cnv[4];
        #pragma unroll
        for (int j = 0; j < 4; ++j)
            cnv[j] = cN[n0 + wn * 64 + j * 16 + l15];
        #pragma unroll
        for (int i = 0; i < 4; ++i) {
            int mb = m0 + wm * 64 + i * 16 + quad * 4;
            #pragma unroll
            for (int r = 0; r < 4; ++r) {
                int m = mb + r;
                float rn = rN[m];
                float s = 0.f;
                #pragma unroll
                for (int j = 0; j < 4; ++j) {
                    int n = n0 + wn * 64 + j * 16 + l15;
                    float g = acc[i][j][r];
                    float ratio = (g * g) / (rn * cnv[j]);
                    float o = __powf(ratio, P_EXP) - ((m == n) ? 1.f : 0.f);
                    float v = fmaxf(0.5f - 0.5f * __cosf(PI_F * o), 0.f);
                    unsigned short e = f2bf_rne(__expf(v));
                    C[(long)m * ldC + n] = e;
                    s += bf2f(e);
                }
                s += __shfl_xor(s, 1);
                s += __shfl_xor(s, 2);
                s += __shfl_xor(s, 4);
                s += __shfl_xor(s, 8);
                if (l15 == 0) atomicAdd(Zp + m, s);
            }
        }
    } else { // EPI_RESID
        float* C = (float*)Cv + (long)bz * sCb;
        const float* Rs = resid + (long)bz * sRb;
        #pragma unroll
        for (int j = 0; j < 4; ++j) {
            int n = n0 + wn * 64 + j * 16 + l15;
            #pragma unroll
            for (int i = 0; i < 4; ++i) {
                int mb = m0 + wm * 64 + i * 16 + quad * 4;
                #pragma unroll
                for (int r = 0; r < 4; ++r) {
                    int m = mb + r;
                    C[(long)m * ldC + n] = (acc[i][j][r] + Rs[(long)m * ldC + n]) * 0.5f;
                }
            }
        }
    }
}

// Zero-init for fused accumulators (count = grid*256 float4s).
__global__ __launch_bounds__(256)
void zero_f4(float4* __restrict__ p)
{
    p[(long)blockIdx.x * 256 + threadIdx.x] = float4{0.f, 0.f, 0.f, 0.f};
}

// ---------------------------------------------------------------------------
// Transpose-cast: in (nb, R, C) [TI = float or bf16] -> out (nb, C, R) bf16.
// ---------------------------------------------------------------------------
template<typename TI>
__global__ __launch_bounds__(256)
void transpose_cast(const TI* __restrict__ in, bf* __restrict__ outp, int R, int C)
{
    __shared__ float tile[32][33];
    long base = (long)blockIdx.z * R * C;
    int r0 = blockIdx.y * 32, c0 = blockIdx.x * 32;
    int tx = threadIdx.x & 31, ty = threadIdx.x >> 5;
    #pragma unroll
    for (int i = 0; i < 4; ++i)
        tile[ty + 8 * i][tx] = (float)in[base + (long)(r0 + ty + 8 * i) * C + c0 + tx];
    __syncthreads();
    #pragma unroll
    for (int i = 0; i < 4; ++i)
        outp[base + (long)(c0 + ty + 8 * i) * R + r0 + tx] = __float2bfloat16(tile[tx][ty + 8 * i]);
}

// Transpose + per-source-row scale: out[c,r] = in[r,c] / Z[r]  (bf16 -> bf16),
// out-of-place, square R==C per batch. Finishes the channel softmax.
__global__ __launch_bounds__(256)
void transpose_scale(const unsigned short* __restrict__ in, const float* __restrict__ Z,
                     unsigned short* __restrict__ outp, int R)
{
    __shared__ float tile[32][33];
    long base = (long)blockIdx.z * R * R;
    const float* Zb = Z + (long)blockIdx.z * R;
    int r0 = blockIdx.y * 32, c0 = blockIdx.x * 32;
    int tx = threadIdx.x & 31, ty = threadIdx.x >> 5;
    #pragma unroll
    for (int i = 0; i < 4; ++i)
        tile[ty + 8 * i][tx] = bf2f(in[base + (long)(r0 + ty + 8 * i) * R + c0 + tx]);
    __syncthreads();
    float inv = 1.f / Zb[r0 + tx];
    #pragma unroll
    for (int i = 0; i < 4; ++i)
        outp[base + (long)(c0 + ty + 8 * i) * R + r0 + tx] = f2bf_rne(tile[tx][ty + 8 * i] * inv);
}

// In-place square transpose of (nb, Ln, Ln) bf16 with per-source-row scale:
// G <- (G / Z[row])^T. Finishes the token softmax during the transpose pass.
__global__ __launch_bounds__(256)
void scaleT_ip(unsigned short* __restrict__ G, const float* __restrict__ Z)
{
    int bi = blockIdx.y, bj = blockIdx.x;
    if (bj < bi) return;
    long base = (long)blockIdx.z * LLm;
    const float* Zb = Z + (long)blockIdx.z * Ln;
    __shared__ unsigned short t1[32][33], t2[32][33];
    int tx = threadIdx.x & 31, ty = threadIdx.x >> 5;
    int r0 = bi * 32, c0 = bj * 32;
    #pragma unroll
    for (int i = 0; i < 4; ++i)
        t1[ty + 8 * i][tx] = G[base + (long)(r0 + ty + 8 * i) * Ln + c0 + tx];
    if (bi != bj) {
        #pragma unroll
        for (int i = 0; i < 4; ++i)
            t2[ty + 8 * i][tx] = G[base + (long)(c0 + ty + 8 * i) * Ln + r0 + tx];
    }
    __syncthreads();
    float invA = 1.f / Zb[r0 + tx];   // scale for values from source row r0+tx
    #pragma unroll
    for (int i = 0; i < 4; ++i)
        G[base + (long)(c0 + ty + 8 * i) * Ln + r0 + tx] =
            f2bf_rne(bf2f(t1[tx][ty + 8 * i]) * invA);
    if (bi != bj) {
        float invB = 1.f / Zb[c0 + tx];
        #pragma unroll
        for (int i = 0; i < 4; ++i)
            G[base + (long)(r0 + ty + 8 * i) * Ln + c0 + tx] =
                f2bf_rne(bf2f(t2[tx][ty + 8 * i]) * invB);
    }
}

// Batched weight cast: W1b4/W2b4[k] = bf16(Wk[layer*DDm]), layer in {1,2}
__global__ __launch_bounds__(256)
void cast_w12(P4 w, bf* __restrict__ w1b4, bf* __restrict__ w2b4)
{
    long i = (long)blockIdx.x * 256 + threadIdx.x;   // over DDm/4
    int layer = blockIdx.y, k = blockIdx.z;
    const float4* src = (const float4*)(w.p[k] + (long)(layer + 1) * DDm);
    ushort4* dst = (ushort4*)((layer ? w2b4 : w1b4) + (long)k * DDm);
    float4 v = src[i];
    ushort4 o; o.x = f2bf_rne(v.x); o.y = f2bf_rne(v.y); o.z = f2bf_rne(v.z); o.w = f2bf_rne(v.w);
    dst[i] = o;
}

// Batched W0 transpose-cast: w0t4[k] = bf16(Wk[0]^T)
__global__ __launch_bounds__(256)
void transpose_w0(P4 w, bf* __restrict__ w0t4)
{
    __shared__ float tile[32][33];
    int k = blockIdx.z;
    const float* in = w.p[k];
    bf* outp = w0t4 + (long)k * DDm;
    int r0 = blockIdx.y * 32, c0 = blockIdx.x * 32;
    int tx = threadIdx.x & 31, ty = threadIdx.x >> 5;
    #pragma unroll
    for (int i = 0; i < 4; ++i)
        tile[ty + 8 * i][tx] = in[(long)(r0 + ty + 8 * i) * Dn + c0 + tx];
    __syncthreads();
    #pragma unroll
    for (int i = 0; i < 4; ++i)
        outp[(long)(c0 + ty + 8 * i) * Dn + r0 + tx] = __float2bfloat16(tile[tx][ty + 8 * i]);
}

// Batched bias compose. stage 0: out4[k]=W1_k*b0_k+b1_k; stage 1: out4[k]=W2_k*vin4[k]+b2_k
__global__ __launch_bounds__(256)
void matvec4(P4 w, P4 b, const float* __restrict__ vin4, float* __restrict__ out4, int stage)
{
    int k = blockIdx.y, o = blockIdx.x;
    const float* W = w.p[k] + (long)(stage ? 2 : 1) * DDm + (long)o * Dn;
    const float* v = stage ? (vin4 + (long)k * Dn) : b.p[k];
    const float* c = b.p[k] + (long)(stage ? 2 : 1) * Dn;
    float s = 0.f;
    for (int i = threadIdx.x; i < Dn; i += 256) s += W[i] * v[i];
    __shared__ float red[256];
    red[threadIdx.x] = s; __syncthreads();
    for (int off = 128; off > 0; off >>= 1) {
        if (threadIdx.x < off) red[threadIdx.x] += red[threadIdx.x + off];
        __syncthreads();
    }
    if (threadIdx.x == 0) out4[(long)k * Dn + o] = red[0] + c[o];
}

// ---------------------------------------------------------------------------
// Host-side GEMM dispatch
// ---------------------------------------------------------------------------
static void glaunch(hipStream_t st, int epi,
                    const bf* A, long sAb, int ldA,
                    const bf* Bt, long sBb, int ldB,
                    void* C, long sCb, int ldC,
                    const float* bias, const float* rowN, const float* colN,
                    const float* resid, long sRb,
                    int M, int N, int K, int nb)
{
    dim3 g(N / 128, M / 128, nb), blk(256);
    const short* As = (const short*)A;
    const short* Bs = (const short*)Bt;
    switch (epi) {
    case EPI_BIAS:    gemm_nt<EPI_BIAS>   <<<g, blk, 0, st>>>(As, sAb, ldA, Bs, sBb, ldB, C, sCb, ldC, bias, rowN, colN, resid, sRb, M, N, K); break;
    case EPI_BIASM:   gemm_nt<EPI_BIASM>  <<<g, blk, 0, st>>>(As, sAb, ldA, Bs, sBb, ldB, C, sCb, ldC, bias, rowN, colN, resid, sRb, M, N, K); break;
    case EPI_PLAIN:   gemm_nt<EPI_PLAIN>  <<<g, blk, 0, st>>>(As, sAb, ldA, Bs, sBb, ldB, C, sCb, ldC, bias, rowN, colN, resid, sRb, M, N, K); break;
    case EPI_CAUCHYB: gemm_nt<EPI_CAUCHYB><<<g, blk, 0, st>>>(As, sAb, ldA, Bs, sBb, ldB, C, sCb, ldC, bias, rowN, colN, resid, sRb, M, N, K); break;
    default:          gemm_nt<EPI_RESID>  <<<g, blk, 0, st>>>(As, sAb, ldA, Bs, sBb, ldB, C, sCb, ldC, bias, rowN, colN, resid, sRb, M, N, K); break;
    }
}

extern "C" void kernel_launch(void* const* d_in, const int* in_sizes, int n_in,
                              void* d_out, int out_size, void* d_ws, size_t ws_size,
                              hipStream_t stream)
{
    const float* x = (const float*)d_in[0];
    float* out = (float*)d_out;

    // Arena (bytes), total 159,600,640:
    //   x_t   [0,          33,554,432)  (B,L,D) bf16; token phase: Gl half (4 x L x L bf16)
    //   dscore[33,554,432, 50,331,648)  (B,D,D) bf16
    //   Weff  [50,331,648, 58,720,256)  4 x (D,D) bf16
    //         NOTE: Weff[0:192K] (k=0,1 head) is reused for ns_l/nc_l/Zl AFTER
    //         the channel GEMM (its last reader of Weff[0:2DDm]).
    //   beff  [58,720,256, +16K) b01_4 [+16K, +32K)
    //   ns_d/nc_d/Zd [58,753,024, +96K)   (ends 58,851,328 < O1: no overlap)
    //   O1    [58,937,344, 126,046,208) 67MB: compose staging / dsdc / Ed? no:
    //         dsdc concat / lslc concat
    //   O2    [126,046,208,159,600,640) 33.5MB: Ed bf16 (head) / t1 bf16
    uint8_t* wsb = (uint8_t*)d_ws;
    if (ws_size < 159600640u) return;

    bf*    x_t    = (bf*)(wsb + 0);
    bf*    dscore = (bf*)(wsb + 33554432);
    bf*    Weff   = (bf*)(wsb + 50331648);
    float* beff   = (float*)(wsb + 58720256);    // 4 x D
    float* b01_4  = (float*)(wsb + 58736640);    // 4 x D
    float* ns_d   = (float*)(wsb + 58753024);    // B*D
    float* nc_d   = ns_d + (long)Bn * Dn;        // B*D
    float* Zd     = nc_d + (long)Bn * Dn;        // B*D   (ends 58,851,328)
    float* ns_l   = (float*)Weff;                // B*L   (valid after channel GEMM)
    float* nc_l   = ns_l + (long)Bn * Ln;        // B*L
    float* Zl     = nc_l + (long)Bn * Ln;        // B*L   (ends +192K into Weff)
    uint8_t* O1   = wsb + 58937344;              // 67,108,864
    uint8_t* O2   = wsb + 126046208;             // 33,554,432

    // O1 sub-layouts (time-disjoint)
    bf* W1b4 = (bf*)O1;                // compose staging: 5 x 4*DDm shorts = 40MB
    bf* W2b4 = W1b4 + 4 * DDm;
    bf* W0t4 = W1b4 + 8 * DDm;
    bf* Zb4  = W1b4 + 12 * DDm;
    bf* Zt4  = W1b4 + 16 * DDm;
    bf* dsdc = (bf*)O1;                // (B, 2D, L) bf16 = 67MB
    bf* lslc = (bf*)O1;                // (B, L, 2D) bf16 = 67MB

    bf* Ed = (bf*)O2;                  // (B, D, D) bf16 exp-scores (head of O2)
    bf* t1 = (bf*)O2;                  // (B, D, L) bf16 (after Ed dead)
    bf* Gl = x_t;                      // token phase: 4 x (L, L) bf16 (x_t dead)

    P4 W, Bv;
    for (int k = 0; k < 4; ++k) { W.p[k] = (const float*)d_in[1 + 2 * k]; Bv.p[k] = (const float*)d_in[2 + 2 * k]; }

    // ---- x transpose-cast: (B,D,L) f32 -> (B,L,D) bf16 ----
    transpose_cast<float><<<dim3(Ln / 32, Dn / 32, Bn), 256, 0, stream>>>(x, x_t, Dn, Ln);

    // ---- zero channel accumulators ns_d/nc_d/Zd (96 KB = 6144 float4) ----
    zero_f4<<<dim3(24), 256, 0, stream>>>((float4*)ns_d);

    // ---- weight staging (batched) + bias compose ----
    cast_w12<<<dim3((unsigned)(DDm / 4 / 256), 2, 4), 256, 0, stream>>>(W, W1b4, W2b4);
    transpose_w0<<<dim3(Dn / 32, Dn / 32, 4), 256, 0, stream>>>(W, W0t4);
    matvec4<<<dim3(Dn, 4), 256, 0, stream>>>(W, Bv, nullptr, b01_4, 0);
    matvec4<<<dim3(Dn, 4), 256, 0, stream>>>(W, Bv, b01_4, beff, 1);

    // ---- compose Weff = W2*W1*W0 (nb=4 batched) ----
    glaunch(stream, EPI_PLAIN, W1b4, DDm, Dn, W0t4, DDm, Dn, Zb4, DDm, Dn,
            nullptr, nullptr, nullptr, nullptr, 0, Dn, Dn, Dn, 4);
    transpose_cast<bf><<<dim3(Dn / 32, Dn / 32, 4), 256, 0, stream>>>(Zb4, Zt4, Dn, Dn);
    glaunch(stream, EPI_PLAIN, W2b4, DDm, Dn, Zt4, DDm, Dn, Weff, DDm, Dn,
            nullptr, nullptr, nullptr, nullptr, 0, Dn, Dn, Dn, 4);

    // ---- channel branch: dsx||dcx concat GEMM + fused sum-of-squares ----
    glaunch(stream, EPI_BIASM, Weff, 0, Dn, x_t, DL, Dn, dsdc, 2 * DL, Ln,
            beff, ns_d, nc_d, nullptr, 0, 2 * Dn, Ln, Dn, Bn);

    // Weff[0:2DDm] now dead -> zero token accumulators ns_l/nc_l/Zl (192 KB)
    zero_f4<<<dim3(48), 256, 0, stream>>>((float4*)ns_l);

    // Ed = exp(cauchy(dcx @ dsx^T)) bf16 + fused row sums Zd
    glaunch(stream, EPI_CAUCHYB, dsdc + DL, 2 * DL, Ln, dsdc, 2 * DL, Ln, Ed, DDm, Dn,
            nullptr, nc_d, ns_d, (const float*)Zd, 0, Dn, Dn, Ln, Bn);
    // dscore = (Ed / Zd[row])^T  (finishes the channel softmax + transpose)
    transpose_scale<<<dim3(Dn / 32, Dn / 32, Bn), 256, 0, stream>>>(
        (const unsigned short*)Ed, Zd, (unsigned short*)dscore, Dn);

    // ---- token branch: lsx_t||lcx_t concat GEMM + fused sum-of-squares ----
    glaunch(stream, EPI_BIAS, x_t, DL, Dn, Weff + 2 * DDm, 0, Dn, lslc, 2 * DL, 2 * Dn,
            beff + 2 * Dn, ns_l, nc_l, nullptr, 0, Ln, 2 * Dn, Dn, Bn);

    // t1 = dscore @ x, all 8 batches (Ed dead, O2 becomes t1)
    glaunch(stream, EPI_PLAIN, dscore, DDm, Dn, x_t, DL, Dn, t1, DL, Ln,
            nullptr, nullptr, nullptr, nullptr, 0, Dn, Ln, Dn, Bn);

    // ---- token score + apply, in 4-batch halves ----
    for (int h = 0; h < 2; ++h) {
        long bo = 4L * h;
        const bf* lsx = lslc + bo * 2 * DL;
        const bf* lcx = lsx + Dn;
        // Gl half = exp(cauchy(lsx^T @ lcx)) bf16 + fused row sums Zl
        glaunch(stream, EPI_CAUCHYB, lsx, 2 * DL, 2 * Dn, lcx, 2 * DL, 2 * Dn,
                Gl, LLm, Ln, nullptr, ns_l + bo * Ln, nc_l + bo * Ln,
                (const float*)(Zl + bo * Ln), 0, Ln, Ln, Dn, 4);
        // Gl <- (Gl / Zl[row])^T in place (finishes token softmax + transpose)
        scaleT_ip<<<dim3(Ln / 32, Ln / 32, 4), 256, 0, stream>>>(
            (unsigned short*)Gl, Zl + bo * Ln);
        // out = (t1 @ lscore + x) / 2
        glaunch(stream, EPI_RESID, t1 + bo * DL, DL, Ln, Gl, LLm, Ln,
                out + bo * DL, DL, Ln, nullptr, nullptr, nullptr, x + bo * DL, DL,
                Dn, Ln, Ln, 4);
    }
}

// Round 6
// 812.437 us; speedup vs baseline: 1.7078x; 1.2351x over previous
//
#include <hip/hip_runtime.h>
#include <hip/hip_bf16.h>
#include <math.h>

// Problem constants
static constexpr int  Bn = 8, Dn = 1024, Ln = 2048;
static constexpr long DL  = (long)Dn * Ln;
static constexpr long DDm = (long)Dn * Dn;
static constexpr long LLm = (long)Ln * Ln;
static constexpr float P_EXP = 1.01005016708416805754f; // exp(0.01)

using bf = __hip_bfloat16;
typedef short s16x8 __attribute__((ext_vector_type(8)));   // 8 bf16 = 4 VGPRs (MFMA A/B frag)
typedef float f32x4 __attribute__((ext_vector_type(4)));   // MFMA C/D frag

#define GPTR(x) ((const __attribute__((address_space(1))) void*)(x))
#define LPTR(x) ((__attribute__((address_space(3))) void*)(x))

enum { EPI_BIAS = 0, EPI_PLAIN = 1, EPI_RESID = 3, EPI_BIASM = 4, EPI_CAUCHYB = 5, EPI_CAUCHYBT = 6 };

// bf16 RNE pack (finite values only)
static __device__ inline unsigned short f2bf_rne(float f)
{
    union { float f; unsigned u; } uf; uf.f = f;
    unsigned r = uf.u + 0x7fff + ((uf.u >> 16) & 1);
    return (unsigned short)(r >> 16);
}
static __device__ inline float bf2f(unsigned short s)
{
    union { unsigned u; float f; } uf; uf.u = ((unsigned)s) << 16;
    return uf.f;
}

struct P4 { const float* p[4]; };

// ---------------------------------------------------------------------------
// NT bf16 MFMA GEMM: C[b,m,n] = sum_k A[b,m,k] * Bt[b,n,k]   (both k-contig)
// 128x128 tile, BK=32, 256 threads (4 waves, 2x2 of 64x64 wave tiles),
// global_load_lds width-16 staging, swizzled LDS k-chunks.
// launch_bounds(256,4): 4 resident blocks/CU -> epilogue overlaps other
// blocks' K-loops (incl. the transcendental CAUCHY epilogues).
//
// Fused epilogues:
//  BIAS/BIASM: store bf16(acc+bias) + per-row sum-of-squares of the STORED
//    values into rowN/colN (split by half) via shfl+atomicAdd.
//  CAUCHYB/CAUCHYBT: exact rewrite of
//      v = relu(0.5-0.5cos(pi*((g^2/(rn*cn))^P - diag)))  (v in [0,1])
//    as  v = sin^2(pi*(o-diag)/2),  o/4 = exp2(2P*log2|g| - P*log2 rn
//                                              - P*log2 cn - 2)
//    (relu is a no-op on a square; Cauchy-Schwarz keeps o<=~1 so v_sin's
//    argument -- in revolutions, sin(2*pi*z) -- stays tiny).
//    v_log/v_exp via __builtin_amdgcn_{logf,exp2f} (HIP has no __exp2f).
//    Store bf16(exp(v)); fused Z sums of the STORED values via atomicAdd:
//      CAUCHYB : Z[m] = row sums   (channel branch)
//      CAUCHYBT: Z[n] = column sums (token branch, which stores E^T)
// ---------------------------------------------------------------------------
template<int EPI>
__global__ __launch_bounds__(256, 4)
void gemm_nt(const short* __restrict__ A, long sAb, int ldA,
             const short* __restrict__ Bt, long sBb, int ldB,
             void* __restrict__ Cv, long sCb, int ldC,
             const float* __restrict__ bias,
             const float* __restrict__ rowN, const float* __restrict__ colN,
             const float* __restrict__ resid, long sRb,
             int M, int N, int K)
{
    __shared__ short As[128 * 32];   // row-major, 32 bf16 per row, k-chunk swizzled
    __shared__ short Bs[128 * 32];

    const int tid  = threadIdx.x;
    const int lane = tid & 63;
    const int w    = tid >> 6;           // wave 0..3
    const int wm   = w >> 1, wn = w & 1; // 2x2 wave grid
    const int m0   = blockIdx.y * 128;
    const int n0   = blockIdx.x * 128;
    const int bz   = blockIdx.z;

    const short* Ab = A  + (long)bz * sAb;
    const short* Bb = Bt + (long)bz * sBb;

    const int srow = lane >> 2;                                  // 0..15 row within 16-row chunk
    const int kc   = ((lane & 3) + 4 - ((lane >> 3) & 3)) & 3;   // swizzled global k-chunk
    const int quad = lane >> 4;
    const int l15  = lane & 15;

    // LDS read offsets (shorts) for the 4 A / 4 B fragments
    int aoff[4], boff[4];
    #pragma unroll
    for (int i = 0; i < 4; ++i) {
        int rA = wm * 64 + i * 16 + l15;
        aoff[i] = rA * 32 + (((quad + (rA >> 1)) & 3) << 3);
        int rB = wn * 64 + i * 16 + l15;
        boff[i] = rB * 32 + (((quad + (rB >> 1)) & 3) << 3);
    }

    // staging: wave w owns 1KB chunks {2w, 2w+1} of both A and B tiles
    const int  ca0 = 2 * w;
    const long gA0 = (long)(m0 + ca0 * 16 + srow)       * ldA + kc * 8;
    const long gA1 = (long)(m0 + (ca0 + 1) * 16 + srow) * ldA + kc * 8;
    const long gB0 = (long)(n0 + ca0 * 16 + srow)       * ldB + kc * 8;
    const long gB1 = (long)(n0 + (ca0 + 1) * 16 + srow) * ldB + kc * 8;
    short* lA0 = As + ca0 * 512;
    short* lA1 = As + ca0 * 512 + 512;
    short* lB0 = Bs + ca0 * 512;
    short* lB1 = Bs + ca0 * 512 + 512;

    f32x4 acc[4][4] = {};

    for (int k0 = 0; k0 < K; k0 += 32) {
        __builtin_amdgcn_global_load_lds(GPTR(Ab + gA0 + k0), LPTR(lA0), 16, 0, 0);
        __builtin_amdgcn_global_load_lds(GPTR(Ab + gA1 + k0), LPTR(lA1), 16, 0, 0);
        __builtin_amdgcn_global_load_lds(GPTR(Bb + gB0 + k0), LPTR(lB0), 16, 0, 0);
        __builtin_amdgcn_global_load_lds(GPTR(Bb + gB1 + k0), LPTR(lB1), 16, 0, 0);
        __syncthreads();

        s16x8 af[4], bfr[4];
        #pragma unroll
        for (int i = 0; i < 4; ++i) af[i]  = *(const s16x8*)(As + aoff[i]);
        #pragma unroll
        for (int j = 0; j < 4; ++j) bfr[j] = *(const s16x8*)(Bs + boff[j]);
        #pragma unroll
        for (int i = 0; i < 4; ++i)
            #pragma unroll
            for (int j = 0; j < 4; ++j)
                acc[i][j] = __builtin_amdgcn_mfma_f32_16x16x32_bf16(af[i], bfr[j], acc[i][j], 0, 0, 0);
        __syncthreads();
    }

    // Epilogue. C/D layout: col = lane&15, row = quad*4 + r within each 16x16.
    if constexpr (EPI == EPI_BIAS || EPI == EPI_PLAIN || EPI == EPI_BIASM) {
        bf* C = (bf*)Cv + (long)bz * sCb;
        #pragma unroll
        for (int i = 0; i < 4; ++i) {
            int mb = m0 + wm * 64 + i * 16 + quad * 4;
            #pragma unroll
            for (int r = 0; r < 4; ++r) {
                float s = 0.f;
                #pragma unroll
                for (int j = 0; j < 4; ++j) {
                    int n = n0 + wn * 64 + j * 16 + l15;
                    float bmv = (EPI == EPI_BIAS) ? bias[n]
                              : (EPI == EPI_BIASM) ? bias[mb + r] : 0.f;
                    bf hv = __float2bfloat16(acc[i][j][r] + bmv);
                    C[(long)(mb + r) * ldC + n] = hv;
                    if constexpr (EPI == EPI_BIAS || EPI == EPI_BIASM) {
                        float q = __bfloat162float(hv);
                        s += q * q;
                    }
                }
                if constexpr (EPI == EPI_BIAS || EPI == EPI_BIASM) {
                    if (rowN) {
                        s += __shfl_xor(s, 1);
                        s += __shfl_xor(s, 2);
                        s += __shfl_xor(s, 4);
                        s += __shfl_xor(s, 8);
                        if (l15 == 0) {
                            int m = mb + r;
                            float* dst;
                            if constexpr (EPI == EPI_BIASM)   // split by output row half
                                dst = (m < Dn) ? ((float*)rowN + (long)bz * Dn + m)
                                               : ((float*)colN + (long)bz * Dn + (m - Dn));
                            else                              // split by output col half
                                dst = (n0 < Dn) ? ((float*)rowN + (long)bz * Ln + m)
                                                : ((float*)colN + (long)bz * Ln + m);
                            atomicAdd(dst, s);
                        }
                    }
                }
            }
        }
    } else if constexpr (EPI == EPI_CAUCHYB || EPI == EPI_CAUCHYBT) {
        const float* rN = rowN + (long)bz * M;
        const float* cN = colN + (long)bz * N;
        float* Zp = (float*)resid + (long)bz * (EPI == EPI_CAUCHYBT ? N : M);
        unsigned short* C = (unsigned short*)Cv + (long)bz * sCb;
        const float TWOP = 2.f * P_EXP;
        const bool diagBlk = (m0 == n0);

        float plc2[4];                       // P*log2(cn[j]) + 2
        #pragma unroll
        for (int j = 0; j < 4; ++j)
            plc2[j] = P_EXP * __builtin_amdgcn_logf(cN[n0 + wn * 64 + j * 16 + l15]) + 2.f;

        float scol[4] = {0.f, 0.f, 0.f, 0.f};
        #pragma unroll
        for (int i = 0; i < 4; ++i) {
            int mb = m0 + wm * 64 + i * 16 + quad * 4;
            #pragma unroll
            for (int r = 0; r < 4; ++r) {
                int m = mb + r;
                float plr = P_EXP * __builtin_amdgcn_logf(rN[m]);
                float srow = 0.f;
                #pragma unroll
                for (int j = 0; j < 4; ++j) {
                    int n = n0 + wn * 64 + j * 16 + l15;
                    float g = acc[i][j][r];
                    // o/4 = exp2(2P*log2|g| - P*log2 rn - P*log2 cn - 2)
                    float o4 = __builtin_amdgcn_exp2f(
                        TWOP * __builtin_amdgcn_logf(fabsf(g)) - plr - plc2[j]);
                    float z  = (diagBlk && m == n) ? (o4 - 0.25f) : o4;
                    float h  = __builtin_amdgcn_sinf(z);   // sin(2*pi*z) = sin(pi*(o-diag)/2)
                    float v  = h * h;                      // = 0.5 - 0.5cos(pi*(o-diag)) >= 0
                    bf hv = __float2bfloat16(__expf(v));
                    C[(long)m * ldC + n] = *reinterpret_cast<unsigned short*>(&hv);
                    float ef = __bfloat162float(hv);
                    if constexpr (EPI == EPI_CAUCHYB) srow += ef; else scol[j] += ef;
                }
                if constexpr (EPI == EPI_CAUCHYB) {
                    srow += __shfl_xor(srow, 1);
                    srow += __shfl_xor(srow, 2);
                    srow += __shfl_xor(srow, 4);
                    srow += __shfl_xor(srow, 8);
                    if (l15 == 0) atomicAdd(Zp + m, srow);
                }
            }
        }
        if constexpr (EPI == EPI_CAUCHYBT) {
            #pragma unroll
            for (int j = 0; j < 4; ++j) {
                float s = scol[j];
                s += __shfl_xor(s, 16);
                s += __shfl_xor(s, 32);
                if (lane < 16) atomicAdd(Zp + (n0 + wn * 64 + j * 16 + l15), s);
            }
        }
    } else { // EPI_RESID
        float* C = (float*)Cv + (long)bz * sCb;
        const float* Rs = resid + (long)bz * sRb;
        #pragma unroll
        for (int j = 0; j < 4; ++j) {
            int n = n0 + wn * 64 + j * 16 + l15;
            #pragma unroll
            for (int i = 0; i < 4; ++i) {
                int mb = m0 + wm * 64 + i * 16 + quad * 4;
                #pragma unroll
                for (int r = 0; r < 4; ++r) {
                    int m = mb + r;
                    C[(long)m * ldC + n] = (acc[i][j][r] + Rs[(long)m * ldC + n]) * 0.5f;
                }
            }
        }
    }
}

// Zero-init for fused accumulators (count = grid*256 float4s).
__global__ __launch_bounds__(256)
void zero_f4(float4* __restrict__ p)
{
    p[(long)blockIdx.x * 256 + threadIdx.x] = float4{0.f, 0.f, 0.f, 0.f};
}

// Scale rows of a (4, Dn, Ln) bf16 tensor by 1/Z[bz, col]: t1[d, r] *= 1/Z[r].
// Finishes the token softmax on the t1 side (sum_r t1[r]/Z[r] * E[r,c]).
__global__ __launch_bounds__(256)
void scale_rows(unsigned short* __restrict__ t1h, const float* __restrict__ Zh)
{
    int d = blockIdx.x, bz = blockIdx.y;
    unsigned short* p = t1h + (long)bz * DL + (long)d * Ln;
    const float* Z = Zh + (long)bz * Ln;
    int c = threadIdx.x * 8;
    s16x8 v = *(const s16x8*)(p + c);
    s16x8 o;
    #pragma unroll
    for (int j = 0; j < 8; ++j) {
        bf hv = __float2bfloat16(bf2f((unsigned short)v[j]) / Z[c + j]);
        o[j] = *reinterpret_cast<short*>(&hv);
    }
    *(s16x8*)(p + c) = o;
}

// ---------------------------------------------------------------------------
// Transpose-cast: in (nb, R, C) [TI = float or bf16] -> out (nb, C, R) bf16.
// ---------------------------------------------------------------------------
template<typename TI>
__global__ __launch_bounds__(256)
void transpose_cast(const TI* __restrict__ in, bf* __restrict__ outp, int R, int C)
{
    __shared__ float tile[32][33];
    long base = (long)blockIdx.z * R * C;
    int r0 = blockIdx.y * 32, c0 = blockIdx.x * 32;
    int tx = threadIdx.x & 31, ty = threadIdx.x >> 5;
    #pragma unroll
    for (int i = 0; i < 4; ++i)
        tile[ty + 8 * i][tx] = (float)in[base + (long)(r0 + ty + 8 * i) * C + c0 + tx];
    __syncthreads();
    #pragma unroll
    for (int i = 0; i < 4; ++i)
        outp[base + (long)(c0 + ty + 8 * i) * R + r0 + tx] = __float2bfloat16(tile[tx][ty + 8 * i]);
}

// Transpose + per-source-row scale: out[c,r] = in[r,c] / Z[r]  (bf16 -> bf16),
// out-of-place, square R==C per batch. Finishes the channel softmax.
__global__ __launch_bounds__(256)
void transpose_scale(const unsigned short* __restrict__ in, const float* __restrict__ Z,
                     unsigned short* __restrict__ outp, int R)
{
    __shared__ float tile[32][33];
    long base = (long)blockIdx.z * R * R;
    const float* Zb = Z + (long)blockIdx.z * R;
    int r0 = blockIdx.y * 32, c0 = blockIdx.x * 32;
    int tx = threadIdx.x & 31, ty = threadIdx.x >> 5;
    #pragma unroll
    for (int i = 0; i < 4; ++i)
        tile[ty + 8 * i][tx] = bf2f(in[base + (long)(r0 + ty + 8 * i) * R + c0 + tx]);
    __syncthreads();
    float inv = 1.f / Zb[r0 + tx];
    #pragma unroll
    for (int i = 0; i < 4; ++i)
        outp[base + (long)(c0 + ty + 8 * i) * R + r0 + tx] = f2bf_rne(tile[tx][ty + 8 * i] * inv);
}

// Batched weight cast: W1b4/W2b4[k] = bf16(Wk[layer*DDm]), layer in {1,2}
__global__ __launch_bounds__(256)
void cast_w12(P4 w, bf* __restrict__ w1b4, bf* __restrict__ w2b4)
{
    long i = (long)blockIdx.x * 256 + threadIdx.x;   // over DDm/4
    int layer = blockIdx.y, k = blockIdx.z;
    const float4* src = (const float4*)(w.p[k] + (long)(layer + 1) * DDm);
    ushort4* dst = (ushort4*)((layer ? w2b4 : w1b4) + (long)k * DDm);
    float4 v = src[i];
    ushort4 o; o.x = f2bf_rne(v.x); o.y = f2bf_rne(v.y); o.z = f2bf_rne(v.z); o.w = f2bf_rne(v.w);
    dst[i] = o;
}

// Batched W0 transpose-cast: w0t4[k] = bf16(Wk[0]^T)
__global__ __launch_bounds__(256)
void transpose_w0(P4 w, bf* __restrict__ w0t4)
{
    __shared__ float tile[32][33];
    int k = blockIdx.z;
    const float* in = w.p[k];
    bf* outp = w0t4 + (long)k * DDm;
    int r0 = blockIdx.y * 32, c0 = blockIdx.x * 32;
    int tx = threadIdx.x & 31, ty = threadIdx.x >> 5;
    #pragma unroll
    for (int i = 0; i < 4; ++i)
        tile[ty + 8 * i][tx] = in[(long)(r0 + ty + 8 * i) * Dn + c0 + tx];
    __syncthreads();
    #pragma unroll
    for (int i = 0; i < 4; ++i)
        outp[(long)(c0 + ty + 8 * i) * Dn + r0 + tx] = __float2bfloat16(tile[tx][ty + 8 * i]);
}

// Batched bias compose. stage 0: out4[k]=W1_k*b0_k+b1_k; stage 1: out4[k]=W2_k*vin4[k]+b2_k
__global__ __launch_bounds__(256)
void matvec4(P4 w, P4 b, const float* __restrict__ vin4, float* __restrict__ out4, int stage)
{
    int k = blockIdx.y, o = blockIdx.x;
    const float* W = w.p[k] + (long)(stage ? 2 : 1) * DDm + (long)o * Dn;
    const float* v = stage ? (vin4 + (long)k * Dn) : b.p[k];
    const float* c = b.p[k] + (long)(stage ? 2 : 1) * Dn;
    float s = 0.f;
    for (int i = threadIdx.x; i < Dn; i += 256) s += W[i] * v[i];
    __shared__ float red[256];
    red[threadIdx.x] = s; __syncthreads();
    for (int off = 128; off > 0; off >>= 1) {
        if (threadIdx.x < off) red[threadIdx.x] += red[threadIdx.x + off];
        __syncthreads();
    }
    if (threadIdx.x == 0) out4[(long)k * Dn + o] = red[0] + c[o];
}

// ---------------------------------------------------------------------------
// Host-side GEMM dispatch
// ---------------------------------------------------------------------------
static void glaunch(hipStream_t st, int epi,
                    const bf* A, long sAb, int ldA,
                    const bf* Bt, long sBb, int ldB,
                    void* C, long sCb, int ldC,
                    const float* bias, const float* rowN, const float* colN,
                    const float* resid, long sRb,
                    int M, int N, int K, int nb)
{
    dim3 g(N / 128, M / 128, nb), blk(256);
    const short* As = (const short*)A;
    const short* Bs = (const short*)Bt;
    switch (epi) {
    case EPI_BIAS:     gemm_nt<EPI_BIAS>    <<<g, blk, 0, st>>>(As, sAb, ldA, Bs, sBb, ldB, C, sCb, ldC, bias, rowN, colN, resid, sRb, M, N, K); break;
    case EPI_BIASM:    gemm_nt<EPI_BIASM>   <<<g, blk, 0, st>>>(As, sAb, ldA, Bs, sBb, ldB, C, sCb, ldC, bias, rowN, colN, resid, sRb, M, N, K); break;
    case EPI_PLAIN:    gemm_nt<EPI_PLAIN>   <<<g, blk, 0, st>>>(As, sAb, ldA, Bs, sBb, ldB, C, sCb, ldC, bias, rowN, colN, resid, sRb, M, N, K); break;
    case EPI_CAUCHYB:  gemm_nt<EPI_CAUCHYB> <<<g, blk, 0, st>>>(As, sAb, ldA, Bs, sBb, ldB, C, sCb, ldC, bias, rowN, colN, resid, sRb, M, N, K); break;
    case EPI_CAUCHYBT: gemm_nt<EPI_CAUCHYBT><<<g, blk, 0, st>>>(As, sAb, ldA, Bs, sBb, ldB, C, sCb, ldC, bias, rowN, colN, resid, sRb, M, N, K); break;
    default:           gemm_nt<EPI_RESID>   <<<g, blk, 0, st>>>(As, sAb, ldA, Bs, sBb, ldB, C, sCb, ldC, bias, rowN, colN, resid, sRb, M, N, K); break;
    }
}

extern "C" void kernel_launch(void* const* d_in, const int* in_sizes, int n_in,
                              void* d_out, int out_size, void* d_ws, size_t ws_size,
                              hipStream_t stream)
{
    const float* x = (const float*)d_in[0];
    float* out = (float*)d_out;

    // Arena (bytes), total 159,600,640:
    //   x_t   [0,          33,554,432)  (B,L,D) bf16; token phase: Gl half (4 x L x L bf16)
    //   dscore[33,554,432, 50,331,648)  (B,D,D) bf16
    //   Weff  [50,331,648, 58,720,256)  4 x (D,D) bf16
    //         NOTE: Weff[0:192K] is reused for ns_l/nc_l/Zl AFTER the channel
    //         GEMM (last reader of Weff[0:2DDm]); token GEMM reads Weff+2DDm.
    //   beff  [58,720,256, +16K) b01_4 [+16K, +32K)
    //   ns_d/nc_d/Zd [58,753,024, +96K)   (ends 58,851,328 < O1: no overlap)
    //   O1    [58,937,344, 126,046,208) 67MB: compose staging / dsdc / lslc
    //   O2    [126,046,208,159,600,640) 33.5MB: Ed bf16 (head) / t1 bf16
    uint8_t* wsb = (uint8_t*)d_ws;
    if (ws_size < 159600640u) return;

    bf*    x_t    = (bf*)(wsb + 0);
    bf*    dscore = (bf*)(wsb + 33554432);
    bf*    Weff   = (bf*)(wsb + 50331648);
    float* beff   = (float*)(wsb + 58720256);    // 4 x D
    float* b01_4  = (float*)(wsb + 58736640);    // 4 x D
    float* ns_d   = (float*)(wsb + 58753024);    // B*D
    float* nc_d   = ns_d + (long)Bn * Dn;        // B*D
    float* Zd     = nc_d + (long)Bn * Dn;        // B*D   (ends 58,851,328)
    float* ns_l   = (float*)Weff;                // B*L   (valid after channel GEMM)
    float* nc_l   = ns_l + (long)Bn * Ln;        // B*L
    float* Zl     = nc_l + (long)Bn * Ln;        // B*L   (ends +192K into Weff)
    uint8_t* O1   = wsb + 58937344;              // 67,108,864
    uint8_t* O2   = wsb + 126046208;             // 33,554,432

    // O1 sub-layouts (time-disjoint)
    bf* W1b4 = (bf*)O1;                // compose staging: 5 x 4*DDm shorts = 40MB
    bf* W2b4 = W1b4 + 4 * DDm;
    bf* W0t4 = W1b4 + 8 * DDm;
    bf* Zb4  = W1b4 + 12 * DDm;
    bf* Zt4  = W1b4 + 16 * DDm;
    bf* dsdc = (bf*)O1;                // (B, 2D, L) bf16 = 67MB
    bf* lslc = (bf*)O1;                // (B, L, 2D) bf16 = 67MB

    bf* Ed = (bf*)O2;                  // (B, D, D) bf16 exp-scores (head of O2)
    bf* t1 = (bf*)O2;                  // (B, D, L) bf16 (after Ed dead)
    bf* Gl = x_t;                      // token phase: 4 x (L, L) bf16 E^T (x_t dead)

    P4 W, Bv;
    for (int k = 0; k < 4; ++k) { W.p[k] = (const float*)d_in[1 + 2 * k]; Bv.p[k] = (const float*)d_in[2 + 2 * k]; }

    // ---- x transpose-cast: (B,D,L) f32 -> (B,L,D) bf16 ----
    transpose_cast<float><<<dim3(Ln / 32, Dn / 32, Bn), 256, 0, stream>>>(x, x_t, Dn, Ln);

    // ---- zero channel accumulators ns_d/nc_d/Zd (96 KB = 6144 float4) ----
    zero_f4<<<dim3(24), 256, 0, stream>>>((float4*)ns_d);

    // ---- weight staging (batched) + bias compose ----
    cast_w12<<<dim3((unsigned)(DDm / 4 / 256), 2, 4), 256, 0, stream>>>(W, W1b4, W2b4);
    transpose_w0<<<dim3(Dn / 32, Dn / 32, 4), 256, 0, stream>>>(W, W0t4);
    matvec4<<<dim3(Dn, 4), 256, 0, stream>>>(W, Bv, nullptr, b01_4, 0);
    matvec4<<<dim3(Dn, 4), 256, 0, stream>>>(W, Bv, b01_4, beff, 1);

    // ---- compose Weff = W2*W1*W0 (nb=4 batched) ----
    glaunch(stream, EPI_PLAIN, W1b4, DDm, Dn, W0t4, DDm, Dn, Zb4, DDm, Dn,
            nullptr, nullptr, nullptr, nullptr, 0, Dn, Dn, Dn, 4);
    transpose_cast<bf><<<dim3(Dn / 32, Dn / 32, 4), 256, 0, stream>>>(Zb4, Zt4, Dn, Dn);
    glaunch(stream, EPI_PLAIN, W2b4, DDm, Dn, Zt4, DDm, Dn, Weff, DDm, Dn,
            nullptr, nullptr, nullptr, nullptr, 0, Dn, Dn, Dn, 4);

    // ---- channel branch: dsx||dcx concat GEMM + fused sum-of-squares ----
    glaunch(stream, EPI_BIASM, Weff, 0, Dn, x_t, DL, Dn, dsdc, 2 * DL, Ln,
            beff, ns_d, nc_d, nullptr, 0, 2 * Dn, Ln, Dn, Bn);

    // Weff[0:2DDm] now dead -> zero token accumulators ns_l/nc_l/Zl (192 KB)
    zero_f4<<<dim3(48), 256, 0, stream>>>((float4*)ns_l);

    // Ed = exp(cauchy(dcx @ dsx^T)) bf16 + fused row sums Zd
    glaunch(stream, EPI_CAUCHYB, dsdc + DL, 2 * DL, Ln, dsdc, 2 * DL, Ln, Ed, DDm, Dn,
            nullptr, nc_d, ns_d, (const float*)Zd, 0, Dn, Dn, Ln, Bn);
    // dscore = (Ed / Zd[row])^T  (finishes the channel softmax + transpose)
    transpose_scale<<<dim3(Dn / 32, Dn / 32, Bn), 256, 0, stream>>>(
        (const unsigned short*)Ed, Zd, (unsigned short*)dscore, Dn);

    // ---- token branch: lsx_t||lcx_t concat GEMM + fused sum-of-squares ----
    glaunch(stream, EPI_BIAS, x_t, DL, Dn, Weff + 2 * DDm, 0, Dn, lslc, 2 * DL, 2 * Dn,
            beff + 2 * Dn, ns_l, nc_l, nullptr, 0, Ln, 2 * Dn, Dn, Bn);

    // t1 = dscore @ x, all 8 batches (Ed dead, O2 becomes t1)
    glaunch(stream, EPI_PLAIN, dscore, DDm, Dn, x_t, DL, Dn, t1, DL, Ln,
            nullptr, nullptr, nullptr, nullptr, 0, Dn, Ln, Dn, Bn);

    // ---- token score + apply, in 4-batch halves ----
    for (int h = 0; h < 2; ++h) {
        long bo = 4L * h;
        const bf* lsx = lslc + bo * 2 * DL;
        const bf* lcx = lsx + Dn;
        // Gl half = E^T directly: swapped operands (A=lcx, B=lsx) => elementwise
        // transpose; fused COLUMN sums of stored = row sums Z of E.
        glaunch(stream, EPI_CAUCHYBT, lcx, 2 * DL, 2 * Dn, lsx, 2 * DL, 2 * Dn,
                Gl, LLm, Ln, nullptr, nc_l + bo * Ln, ns_l + bo * Ln,
                (const float*)(Zl + bo * Ln), 0, Ln, Ln, Dn, 4);
        // t1[d,r] *= 1/Zl[r]  (moves the softmax normalization onto t1)
        scale_rows<<<dim3(Dn, 4), 256, 0, stream>>>(
            (unsigned short*)(t1 + bo * DL), Zl + bo * Ln);
        // out = (t1' @ E + x) / 2   (Bt = Gl = E^T, k-contig)
        glaunch(stream, EPI_RESID, t1 + bo * DL, DL, Ln, Gl, LLm, Ln,
                out + bo * DL, DL, Ln, nullptr, nullptr, nullptr, x + bo * DL, DL,
                Dn, Ln, Ln, 4);
    }
}

// Round 7
// 761.351 us; speedup vs baseline: 1.8224x; 1.0671x over previous
//
#include <hip/hip_runtime.h>
#include <hip/hip_bf16.h>
#include <math.h>

// Problem constants
static constexpr int  Bn = 8, Dn = 1024, Ln = 2048;
static constexpr long DL  = (long)Dn * Ln;
static constexpr long DDm = (long)Dn * Dn;
static constexpr long LLm = (long)Ln * Ln;
static constexpr float P_EXP = 1.01005016708416805754f; // exp(0.01)

using bf = __hip_bfloat16;
typedef short s16x8 __attribute__((ext_vector_type(8)));   // 8 bf16 = 4 VGPRs (MFMA A/B frag)
typedef float f32x4 __attribute__((ext_vector_type(4)));   // MFMA C/D frag

#define GPTR(x) ((const __attribute__((address_space(1))) void*)(x))
#define LPTR(x) ((__attribute__((address_space(3))) void*)(x))

enum { EPI_BIAS = 0, EPI_PLAIN = 1, EPI_RESID = 3, EPI_BIASM = 4, EPI_CAUCHYB = 5, EPI_CAUCHYBT = 6 };

// bf16 RNE pack (finite values only)
static __device__ inline unsigned short f2bf_rne(float f)
{
    union { float f; unsigned u; } uf; uf.f = f;
    unsigned r = uf.u + 0x7fff + ((uf.u >> 16) & 1);
    return (unsigned short)(r >> 16);
}
static __device__ inline float bf2f(unsigned short s)
{
    union { unsigned u; float f; } uf; uf.u = ((unsigned)s) << 16;
    return uf.f;
}

struct P4 { const float* p[4]; };

// ---------------------------------------------------------------------------
// NT bf16 MFMA GEMM: C[b,m,n] = sum_k A[b,m,k] * Bt[b,n,k]   (both k-contig)
// 128x128 tile, BK=64 as TWO 32-wide k-panels per barrier pair:
//   stage 8 x global_load_lds -> sync -> 2x(frag-read + 16 MFMA) -> sync.
// Halves the per-K barrier drains vs BK=32 (MfmaUtil 28% -> ~40%).
// LDS 32 KB (4 panels of 128x32 bf16), still 4 blocks/CU at launch_bounds(256,4)
// -> epilogues (incl. transcendental CAUCHY) overlap other blocks' K-loops.
//
// Fused epilogues:
//  BIAS/BIASM: store bf16(acc+bias) + per-row sum-of-squares of the STORED
//    values into rowN/colN (split by half) via shfl+atomicAdd.
//  CAUCHYB/CAUCHYBT: exact rewrite of
//      v = relu(0.5-0.5cos(pi*((g^2/(rn*cn))^P - diag)))  (v in [0,1])
//    as  v = sin^2(pi*(o-diag)/2),  o/4 = exp2(2P*log2|g| - P*log2 rn
//                                              - P*log2 cn - 2)
//    (relu is a no-op on a square; Cauchy-Schwarz keeps o<=~1 so v_sin's
//    argument -- in revolutions, sin(2*pi*z) -- stays tiny).
//    v_log/v_exp via __builtin_amdgcn_{logf,exp2f} (HIP has no __exp2f).
//    Store bf16(exp(v)); fused Z sums of the STORED values via atomicAdd:
//      CAUCHYB : Z[m] = row sums   (channel branch)
//      CAUCHYBT: Z[n] = column sums (token branch, which stores E^T)
// ---------------------------------------------------------------------------
template<int EPI>
__global__ __launch_bounds__(256, 4)
void gemm_nt(const short* __restrict__ A, long sAb, int ldA,
             const short* __restrict__ Bt, long sBb, int ldB,
             void* __restrict__ Cv, long sCb, int ldC,
             const float* __restrict__ bias,
             const float* __restrict__ rowN, const float* __restrict__ colN,
             const float* __restrict__ resid, long sRb,
             int M, int N, int K)
{
    __shared__ short As[2 * 128 * 32];   // panel0 | panel1 (each 128 rows x 32 bf16)
    __shared__ short Bs[2 * 128 * 32];

    const int tid  = threadIdx.x;
    const int lane = tid & 63;
    const int w    = tid >> 6;           // wave 0..3
    const int wm   = w >> 1, wn = w & 1; // 2x2 wave grid
    const int m0   = blockIdx.y * 128;
    const int n0   = blockIdx.x * 128;
    const int bz   = blockIdx.z;

    const short* Ab = A  + (long)bz * sAb;
    const short* Bb = Bt + (long)bz * sBb;

    const int srow = lane >> 2;                                  // 0..15 row within 16-row chunk
    const int kc   = ((lane & 3) + 4 - ((lane >> 3) & 3)) & 3;   // swizzled global k-chunk
    const int quad = lane >> 4;
    const int l15  = lane & 15;

    // LDS read offsets (shorts) for the 4 A / 4 B fragments (within a panel)
    int aoff[4], boff[4];
    #pragma unroll
    for (int i = 0; i < 4; ++i) {
        int rA = wm * 64 + i * 16 + l15;
        aoff[i] = rA * 32 + (((quad + (rA >> 1)) & 3) << 3);
        int rB = wn * 64 + i * 16 + l15;
        boff[i] = rB * 32 + (((quad + (rB >> 1)) & 3) << 3);
    }

    // staging: wave w owns 1KB chunks {2w, 2w+1} of both A and B panels
    const int  ca0 = 2 * w;
    const long gA0 = (long)(m0 + ca0 * 16 + srow)       * ldA + kc * 8;
    const long gA1 = (long)(m0 + (ca0 + 1) * 16 + srow) * ldA + kc * 8;
    const long gB0 = (long)(n0 + ca0 * 16 + srow)       * ldB + kc * 8;
    const long gB1 = (long)(n0 + (ca0 + 1) * 16 + srow) * ldB + kc * 8;
    short* lA0 = As + ca0 * 512;
    short* lA1 = As + ca0 * 512 + 512;
    short* lB0 = Bs + ca0 * 512;
    short* lB1 = Bs + ca0 * 512 + 512;

    f32x4 acc[4][4] = {};

    for (int k0 = 0; k0 < K; k0 += 64) {
        // panel 0 (k0) and panel 1 (k0+32): 8 direct-to-LDS loads, one drain
        __builtin_amdgcn_global_load_lds(GPTR(Ab + gA0 + k0),      LPTR(lA0),        16, 0, 0);
        __builtin_amdgcn_global_load_lds(GPTR(Ab + gA1 + k0),      LPTR(lA1),        16, 0, 0);
        __builtin_amdgcn_global_load_lds(GPTR(Bb + gB0 + k0),      LPTR(lB0),        16, 0, 0);
        __builtin_amdgcn_global_load_lds(GPTR(Bb + gB1 + k0),      LPTR(lB1),        16, 0, 0);
        __builtin_amdgcn_global_load_lds(GPTR(Ab + gA0 + k0 + 32), LPTR(lA0 + 4096), 16, 0, 0);
        __builtin_amdgcn_global_load_lds(GPTR(Ab + gA1 + k0 + 32), LPTR(lA1 + 4096), 16, 0, 0);
        __builtin_amdgcn_global_load_lds(GPTR(Bb + gB0 + k0 + 32), LPTR(lB0 + 4096), 16, 0, 0);
        __builtin_amdgcn_global_load_lds(GPTR(Bb + gB1 + k0 + 32), LPTR(lB1 + 4096), 16, 0, 0);
        __syncthreads();

        #pragma unroll
        for (int p = 0; p < 2; ++p) {
            const short* Ap = As + p * 4096;
            const short* Bp = Bs + p * 4096;
            s16x8 af[4], bfr[4];
            #pragma unroll
            for (int i = 0; i < 4; ++i) af[i]  = *(const s16x8*)(Ap + aoff[i]);
            #pragma unroll
            for (int j = 0; j < 4; ++j) bfr[j] = *(const s16x8*)(Bp + boff[j]);
            #pragma unroll
            for (int i = 0; i < 4; ++i)
                #pragma unroll
                for (int j = 0; j < 4; ++j)
                    acc[i][j] = __builtin_amdgcn_mfma_f32_16x16x32_bf16(af[i], bfr[j], acc[i][j], 0, 0, 0);
        }
        __syncthreads();
    }

    // Epilogue. C/D layout: col = lane&15, row = quad*4 + r within each 16x16.
    if constexpr (EPI == EPI_BIAS || EPI == EPI_PLAIN || EPI == EPI_BIASM) {
        bf* C = (bf*)Cv + (long)bz * sCb;
        #pragma unroll
        for (int i = 0; i < 4; ++i) {
            int mb = m0 + wm * 64 + i * 16 + quad * 4;
            #pragma unroll
            for (int r = 0; r < 4; ++r) {
                float s = 0.f;
                #pragma unroll
                for (int j = 0; j < 4; ++j) {
                    int n = n0 + wn * 64 + j * 16 + l15;
                    float bmv = (EPI == EPI_BIAS) ? bias[n]
                              : (EPI == EPI_BIASM) ? bias[mb + r] : 0.f;
                    bf hv = __float2bfloat16(acc[i][j][r] + bmv);
                    C[(long)(mb + r) * ldC + n] = hv;
                    if constexpr (EPI == EPI_BIAS || EPI == EPI_BIASM) {
                        float q = __bfloat162float(hv);
                        s += q * q;
                    }
                }
                if constexpr (EPI == EPI_BIAS || EPI == EPI_BIASM) {
                    if (rowN) {
                        s += __shfl_xor(s, 1);
                        s += __shfl_xor(s, 2);
                        s += __shfl_xor(s, 4);
                        s += __shfl_xor(s, 8);
                        if (l15 == 0) {
                            int m = mb + r;
                            float* dst;
                            if constexpr (EPI == EPI_BIASM)   // split by output row half
                                dst = (m < Dn) ? ((float*)rowN + (long)bz * Dn + m)
                                               : ((float*)colN + (long)bz * Dn + (m - Dn));
                            else                              // split by output col half
                                dst = (n0 < Dn) ? ((float*)rowN + (long)bz * Ln + m)
                                                : ((float*)colN + (long)bz * Ln + m);
                            atomicAdd(dst, s);
                        }
                    }
                }
            }
        }
    } else if constexpr (EPI == EPI_CAUCHYB || EPI == EPI_CAUCHYBT) {
        const float* rN = rowN + (long)bz * M;
        const float* cN = colN + (long)bz * N;
        float* Zp = (float*)resid + (long)bz * (EPI == EPI_CAUCHYBT ? N : M);
        unsigned short* C = (unsigned short*)Cv + (long)bz * sCb;
        const float TWOP = 2.f * P_EXP;
        const bool diagBlk = (m0 == n0);

        float plc2[4];                       // P*log2(cn[j]) + 2
        #pragma unroll
        for (int j = 0; j < 4; ++j)
            plc2[j] = P_EXP * __builtin_amdgcn_logf(cN[n0 + wn * 64 + j * 16 + l15]) + 2.f;

        float scol[4] = {0.f, 0.f, 0.f, 0.f};
        #pragma unroll
        for (int i = 0; i < 4; ++i) {
            int mb = m0 + wm * 64 + i * 16 + quad * 4;
            #pragma unroll
            for (int r = 0; r < 4; ++r) {
                int m = mb + r;
                float plr = P_EXP * __builtin_amdgcn_logf(rN[m]);
                float srow = 0.f;
                #pragma unroll
                for (int j = 0; j < 4; ++j) {
                    int n = n0 + wn * 64 + j * 16 + l15;
                    float g = acc[i][j][r];
                    // o/4 = exp2(2P*log2|g| - P*log2 rn - P*log2 cn - 2)
                    float o4 = __builtin_amdgcn_exp2f(
                        TWOP * __builtin_amdgcn_logf(fabsf(g)) - plr - plc2[j]);
                    float z  = (diagBlk && m == n) ? (o4 - 0.25f) : o4;
                    float h  = __builtin_amdgcn_sinf(z);   // sin(2*pi*z) = sin(pi*(o-diag)/2)
                    float v  = h * h;                      // = 0.5 - 0.5cos(pi*(o-diag)) >= 0
                    bf hv = __float2bfloat16(__expf(v));
                    C[(long)m * ldC + n] = *reinterpret_cast<unsigned short*>(&hv);
                    float ef = __bfloat162float(hv);
                    if constexpr (EPI == EPI_CAUCHYB) srow += ef; else scol[j] += ef;
                }
                if constexpr (EPI == EPI_CAUCHYB) {
                    srow += __shfl_xor(srow, 1);
                    srow += __shfl_xor(srow, 2);
                    srow += __shfl_xor(srow, 4);
                    srow += __shfl_xor(srow, 8);
                    if (l15 == 0) atomicAdd(Zp + m, srow);
                }
            }
        }
        if constexpr (EPI == EPI_CAUCHYBT) {
            #pragma unroll
            for (int j = 0; j < 4; ++j) {
                float s = scol[j];
                s += __shfl_xor(s, 16);
                s += __shfl_xor(s, 32);
                if (lane < 16) atomicAdd(Zp + (n0 + wn * 64 + j * 16 + l15), s);
            }
        }
    } else { // EPI_RESID
        float* C = (float*)Cv + (long)bz * sCb;
        const float* Rs = resid + (long)bz * sRb;
        #pragma unroll
        for (int j = 0; j < 4; ++j) {
            int n = n0 + wn * 64 + j * 16 + l15;
            #pragma unroll
            for (int i = 0; i < 4; ++i) {
                int mb = m0 + wm * 64 + i * 16 + quad * 4;
                #pragma unroll
                for (int r = 0; r < 4; ++r) {
                    int m = mb + r;
                    C[(long)m * ldC + n] = (acc[i][j][r] + Rs[(long)m * ldC + n]) * 0.5f;
                }
            }
        }
    }
}

// Zero-init for fused accumulators (count = grid*256 float4s).
__global__ __launch_bounds__(256)
void zero_f4(float4* __restrict__ p)
{
    p[(long)blockIdx.x * 256 + threadIdx.x] = float4{0.f, 0.f, 0.f, 0.f};
}

// Scale rows of a (4, Dn, Ln) bf16 tensor by 1/Z[bz, col]: t1[d, r] *= 1/Z[r].
// Finishes the token softmax on the t1 side (sum_r t1[r]/Z[r] * E[r,c]).
__global__ __launch_bounds__(256)
void scale_rows(unsigned short* __restrict__ t1h, const float* __restrict__ Zh)
{
    int d = blockIdx.x, bz = blockIdx.y;
    unsigned short* p = t1h + (long)bz * DL + (long)d * Ln;
    const float* Z = Zh + (long)bz * Ln;
    int c = threadIdx.x * 8;
    s16x8 v = *(const s16x8*)(p + c);
    s16x8 o;
    #pragma unroll
    for (int j = 0; j < 8; ++j) {
        bf hv = __float2bfloat16(bf2f((unsigned short)v[j]) / Z[c + j]);
        o[j] = *reinterpret_cast<short*>(&hv);
    }
    *(s16x8*)(p + c) = o;
}

// ---------------------------------------------------------------------------
// Transpose-cast: in (nb, R, C) [TI = float or bf16] -> out (nb, C, R) bf16.
// ---------------------------------------------------------------------------
template<typename TI>
__global__ __launch_bounds__(256)
void transpose_cast(const TI* __restrict__ in, bf* __restrict__ outp, int R, int C)
{
    __shared__ float tile[32][33];
    long base = (long)blockIdx.z * R * C;
    int r0 = blockIdx.y * 32, c0 = blockIdx.x * 32;
    int tx = threadIdx.x & 31, ty = threadIdx.x >> 5;
    #pragma unroll
    for (int i = 0; i < 4; ++i)
        tile[ty + 8 * i][tx] = (float)in[base + (long)(r0 + ty + 8 * i) * C + c0 + tx];
    __syncthreads();
    #pragma unroll
    for (int i = 0; i < 4; ++i)
        outp[base + (long)(c0 + ty + 8 * i) * R + r0 + tx] = __float2bfloat16(tile[tx][ty + 8 * i]);
}

// Transpose + per-source-row scale: out[c,r] = in[r,c] / Z[r]  (bf16 -> bf16),
// out-of-place, square R==C per batch. Finishes the channel softmax.
__global__ __launch_bounds__(256)
void transpose_scale(const unsigned short* __restrict__ in, const float* __restrict__ Z,
                     unsigned short* __restrict__ outp, int R)
{
    __shared__ float tile[32][33];
    long base = (long)blockIdx.z * R * R;
    const float* Zb = Z + (long)blockIdx.z * R;
    int r0 = blockIdx.y * 32, c0 = blockIdx.x * 32;
    int tx = threadIdx.x & 31, ty = threadIdx.x >> 5;
    #pragma unroll
    for (int i = 0; i < 4; ++i)
        tile[ty + 8 * i][tx] = bf2f(in[base + (long)(r0 + ty + 8 * i) * R + c0 + tx]);
    __syncthreads();
    float inv = 1.f / Zb[r0 + tx];
    #pragma unroll
    for (int i = 0; i < 4; ++i)
        outp[base + (long)(c0 + ty + 8 * i) * R + r0 + tx] = f2bf_rne(tile[tx][ty + 8 * i] * inv);
}

// Batched weight cast: W1b4/W2b4[k] = bf16(Wk[layer*DDm]), layer in {1,2}
__global__ __launch_bounds__(256)
void cast_w12(P4 w, bf* __restrict__ w1b4, bf* __restrict__ w2b4)
{
    long i = (long)blockIdx.x * 256 + threadIdx.x;   // over DDm/4
    int layer = blockIdx.y, k = blockIdx.z;
    const float4* src = (const float4*)(w.p[k] + (long)(layer + 1) * DDm);
    ushort4* dst = (ushort4*)((layer ? w2b4 : w1b4) + (long)k * DDm);
    float4 v = src[i];
    ushort4 o; o.x = f2bf_rne(v.x); o.y = f2bf_rne(v.y); o.z = f2bf_rne(v.z); o.w = f2bf_rne(v.w);
    dst[i] = o;
}

// Batched W0 transpose-cast: w0t4[k] = bf16(Wk[0]^T)
__global__ __launch_bounds__(256)
void transpose_w0(P4 w, bf* __restrict__ w0t4)
{
    __shared__ float tile[32][33];
    int k = blockIdx.z;
    const float* in = w.p[k];
    bf* outp = w0t4 + (long)k * DDm;
    int r0 = blockIdx.y * 32, c0 = blockIdx.x * 32;
    int tx = threadIdx.x & 31, ty = threadIdx.x >> 5;
    #pragma unroll
    for (int i = 0; i < 4; ++i)
        tile[ty + 8 * i][tx] = in[(long)(r0 + ty + 8 * i) * Dn + c0 + tx];
    __syncthreads();
    #pragma unroll
    for (int i = 0; i < 4; ++i)
        outp[(long)(c0 + ty + 8 * i) * Dn + r0 + tx] = __float2bfloat16(tile[tx][ty + 8 * i]);
}

// Batched bias compose. stage 0: out4[k]=W1_k*b0_k+b1_k; stage 1: out4[k]=W2_k*vin4[k]+b2_k
__global__ __launch_bounds__(256)
void matvec4(P4 w, P4 b, const float* __restrict__ vin4, float* __restrict__ out4, int stage)
{
    int k = blockIdx.y, o = blockIdx.x;
    const float* W = w.p[k] + (long)(stage ? 2 : 1) * DDm + (long)o * Dn;
    const float* v = stage ? (vin4 + (long)k * Dn) : b.p[k];
    const float* c = b.p[k] + (long)(stage ? 2 : 1) * Dn;
    float s = 0.f;
    for (int i = threadIdx.x; i < Dn; i += 256) s += W[i] * v[i];
    __shared__ float red[256];
    red[threadIdx.x] = s; __syncthreads();
    for (int off = 128; off > 0; off >>= 1) {
        if (threadIdx.x < off) red[threadIdx.x] += red[threadIdx.x + off];
        __syncthreads();
    }
    if (threadIdx.x == 0) out4[(long)k * Dn + o] = red[0] + c[o];
}

// ---------------------------------------------------------------------------
// Host-side GEMM dispatch
// ---------------------------------------------------------------------------
static void glaunch(hipStream_t st, int epi,
                    const bf* A, long sAb, int ldA,
                    const bf* Bt, long sBb, int ldB,
                    void* C, long sCb, int ldC,
                    const float* bias, const float* rowN, const float* colN,
                    const float* resid, long sRb,
                    int M, int N, int K, int nb)
{
    dim3 g(N / 128, M / 128, nb), blk(256);
    const short* As = (const short*)A;
    const short* Bs = (const short*)Bt;
    switch (epi) {
    case EPI_BIAS:     gemm_nt<EPI_BIAS>    <<<g, blk, 0, st>>>(As, sAb, ldA, Bs, sBb, ldB, C, sCb, ldC, bias, rowN, colN, resid, sRb, M, N, K); break;
    case EPI_BIASM:    gemm_nt<EPI_BIASM>   <<<g, blk, 0, st>>>(As, sAb, ldA, Bs, sBb, ldB, C, sCb, ldC, bias, rowN, colN, resid, sRb, M, N, K); break;
    case EPI_PLAIN:    gemm_nt<EPI_PLAIN>   <<<g, blk, 0, st>>>(As, sAb, ldA, Bs, sBb, ldB, C, sCb, ldC, bias, rowN, colN, resid, sRb, M, N, K); break;
    case EPI_CAUCHYB:  gemm_nt<EPI_CAUCHYB> <<<g, blk, 0, st>>>(As, sAb, ldA, Bs, sBb, ldB, C, sCb, ldC, bias, rowN, colN, resid, sRb, M, N, K); break;
    case EPI_CAUCHYBT: gemm_nt<EPI_CAUCHYBT><<<g, blk, 0, st>>>(As, sAb, ldA, Bs, sBb, ldB, C, sCb, ldC, bias, rowN, colN, resid, sRb, M, N, K); break;
    default:           gemm_nt<EPI_RESID>   <<<g, blk, 0, st>>>(As, sAb, ldA, Bs, sBb, ldB, C, sCb, ldC, bias, rowN, colN, resid, sRb, M, N, K); break;
    }
}

extern "C" void kernel_launch(void* const* d_in, const int* in_sizes, int n_in,
                              void* d_out, int out_size, void* d_ws, size_t ws_size,
                              hipStream_t stream)
{
    const float* x = (const float*)d_in[0];
    float* out = (float*)d_out;

    // Arena (bytes), total 159,600,640:
    //   x_t   [0,          33,554,432)  (B,L,D) bf16; token phase: Gl half (4 x L x L bf16)
    //   dscore[33,554,432, 50,331,648)  (B,D,D) bf16
    //   Weff  [50,331,648, 58,720,256)  4 x (D,D) bf16
    //         NOTE: Weff[0:192K] is reused for ns_l/nc_l/Zl AFTER the channel
    //         GEMM (last reader of Weff[0:2DDm]); token GEMM reads Weff+2DDm.
    //   beff  [58,720,256, +16K) b01_4 [+16K, +32K)
    //   ns_d/nc_d/Zd [58,753,024, +96K)   (ends 58,851,328 < O1: no overlap)
    //   O1    [58,937,344, 126,046,208) 67MB: compose staging / dsdc / lslc
    //   O2    [126,046,208,159,600,640) 33.5MB: Ed bf16 (head) / t1 bf16
    uint8_t* wsb = (uint8_t*)d_ws;
    if (ws_size < 159600640u) return;

    bf*    x_t    = (bf*)(wsb + 0);
    bf*    dscore = (bf*)(wsb + 33554432);
    bf*    Weff   = (bf*)(wsb + 50331648);
    float* beff   = (float*)(wsb + 58720256);    // 4 x D
    float* b01_4  = (float*)(wsb + 58736640);    // 4 x D
    float* ns_d   = (float*)(wsb + 58753024);    // B*D
    float* nc_d   = ns_d + (long)Bn * Dn;        // B*D
    float* Zd     = nc_d + (long)Bn * Dn;        // B*D   (ends 58,851,328)
    float* ns_l   = (float*)Weff;                // B*L   (valid after channel GEMM)
    float* nc_l   = ns_l + (long)Bn * Ln;        // B*L
    float* Zl     = nc_l + (long)Bn * Ln;        // B*L   (ends +192K into Weff)
    uint8_t* O1   = wsb + 58937344;              // 67,108,864
    uint8_t* O2   = wsb + 126046208;             // 33,554,432

    // O1 sub-layouts (time-disjoint)
    bf* W1b4 = (bf*)O1;                // compose staging: 5 x 4*DDm shorts = 40MB
    bf* W2b4 = W1b4 + 4 * DDm;
    bf* W0t4 = W1b4 + 8 * DDm;
    bf* Zb4  = W1b4 + 12 * DDm;
    bf* Zt4  = W1b4 + 16 * DDm;
    bf* dsdc = (bf*)O1;                // (B, 2D, L) bf16 = 67MB
    bf* lslc = (bf*)O1;                // (B, L, 2D) bf16 = 67MB

    bf* Ed = (bf*)O2;                  // (B, D, D) bf16 exp-scores (head of O2)
    bf* t1 = (bf*)O2;                  // (B, D, L) bf16 (after Ed dead)
    bf* Gl = x_t;                      // token phase: 4 x (L, L) bf16 E^T (x_t dead)

    P4 W, Bv;
    for (int k = 0; k < 4; ++k) { W.p[k] = (const float*)d_in[1 + 2 * k]; Bv.p[k] = (const float*)d_in[2 + 2 * k]; }

    // ---- x transpose-cast: (B,D,L) f32 -> (B,L,D) bf16 ----
    transpose_cast<float><<<dim3(Ln / 32, Dn / 32, Bn), 256, 0, stream>>>(x, x_t, Dn, Ln);

    // ---- zero channel accumulators ns_d/nc_d/Zd (96 KB = 6144 float4) ----
    zero_f4<<<dim3(24), 256, 0, stream>>>((float4*)ns_d);

    // ---- weight staging (batched) + bias compose ----
    cast_w12<<<dim3((unsigned)(DDm / 4 / 256), 2, 4), 256, 0, stream>>>(W, W1b4, W2b4);
    transpose_w0<<<dim3(Dn / 32, Dn / 32, 4), 256, 0, stream>>>(W, W0t4);
    matvec4<<<dim3(Dn, 4), 256, 0, stream>>>(W, Bv, nullptr, b01_4, 0);
    matvec4<<<dim3(Dn, 4), 256, 0, stream>>>(W, Bv, b01_4, beff, 1);

    // ---- compose Weff = W2*W1*W0 (nb=4 batched) ----
    glaunch(stream, EPI_PLAIN, W1b4, DDm, Dn, W0t4, DDm, Dn, Zb4, DDm, Dn,
            nullptr, nullptr, nullptr, nullptr, 0, Dn, Dn, Dn, 4);
    transpose_cast<bf><<<dim3(Dn / 32, Dn / 32, 4), 256, 0, stream>>>(Zb4, Zt4, Dn, Dn);
    glaunch(stream, EPI_PLAIN, W2b4, DDm, Dn, Zt4, DDm, Dn, Weff, DDm, Dn,
            nullptr, nullptr, nullptr, nullptr, 0, Dn, Dn, Dn, 4);

    // ---- channel branch: dsx||dcx concat GEMM + fused sum-of-squares ----
    glaunch(stream, EPI_BIASM, Weff, 0, Dn, x_t, DL, Dn, dsdc, 2 * DL, Ln,
            beff, ns_d, nc_d, nullptr, 0, 2 * Dn, Ln, Dn, Bn);

    // Weff[0:2DDm] now dead -> zero token accumulators ns_l/nc_l/Zl (192 KB)
    zero_f4<<<dim3(48), 256, 0, stream>>>((float4*)ns_l);

    // Ed = exp(cauchy(dcx @ dsx^T)) bf16 + fused row sums Zd
    glaunch(stream, EPI_CAUCHYB, dsdc + DL, 2 * DL, Ln, dsdc, 2 * DL, Ln, Ed, DDm, Dn,
            nullptr, nc_d, ns_d, (const float*)Zd, 0, Dn, Dn, Ln, Bn);
    // dscore = (Ed / Zd[row])^T  (finishes the channel softmax + transpose)
    transpose_scale<<<dim3(Dn / 32, Dn / 32, Bn), 256, 0, stream>>>(
        (const unsigned short*)Ed, Zd, (unsigned short*)dscore, Dn);

    // ---- token branch: lsx_t||lcx_t concat GEMM + fused sum-of-squares ----
    glaunch(stream, EPI_BIAS, x_t, DL, Dn, Weff + 2 * DDm, 0, Dn, lslc, 2 * DL, 2 * Dn,
            beff + 2 * Dn, ns_l, nc_l, nullptr, 0, Ln, 2 * Dn, Dn, Bn);

    // t1 = dscore @ x, all 8 batches (Ed dead, O2 becomes t1)
    glaunch(stream, EPI_PLAIN, dscore, DDm, Dn, x_t, DL, Dn, t1, DL, Ln,
            nullptr, nullptr, nullptr, nullptr, 0, Dn, Ln, Dn, Bn);

    // ---- token score + apply, in 4-batch halves ----
    for (int h = 0; h < 2; ++h) {
        long bo = 4L * h;
        const bf* lsx = lslc + bo * 2 * DL;
        const bf* lcx = lsx + Dn;
        // Gl half = E^T directly: swapped operands (A=lcx, B=lsx) => elementwise
        // transpose; fused COLUMN sums of stored = row sums Z of E.
        glaunch(stream, EPI_CAUCHYBT, lcx, 2 * DL, 2 * Dn, lsx, 2 * DL, 2 * Dn,
                Gl, LLm, Ln, nullptr, nc_l + bo * Ln, ns_l + bo * Ln,
                (const float*)(Zl + bo * Ln), 0, Ln, Ln, Dn, 4);
        // t1[d,r] *= 1/Zl[r]  (moves the softmax normalization onto t1)
        scale_rows<<<dim3(Dn, 4), 256, 0, stream>>>(
            (unsigned short*)(t1 + bo * DL), Zl + bo * Ln);
        // out = (t1' @ E + x) / 2   (Bt = Gl = E^T, k-contig)
        glaunch(stream, EPI_RESID, t1 + bo * DL, DL, Ln, Gl, LLm, Ln,
                out + bo * DL, DL, Ln, nullptr, nullptr, nullptr, x + bo * DL, DL,
                Dn, Ln, Ln, 4);
    }
}